// Round 1
// baseline (416.415 us; speedup 1.0000x reference)
//
#include <hip/hip_runtime.h>
#include <stdint.h>

#define B_ 2
#define S_ 2048
#define HID_ 2048
#define H_ 16
#define D_ 128
#define LOG2E 1.44269504088896f

typedef __bf16 bf16;
typedef __bf16 bf16x8 __attribute__((ext_vector_type(8)));
typedef __bf16 bf16x4 __attribute__((ext_vector_type(4)));
typedef float floatx4 __attribute__((ext_vector_type(4)));

#define MFMA16(a, b, c) __builtin_amdgcn_mfma_f32_16x16x32_bf16(a, b, c, 0, 0, 0)

__device__ __forceinline__ void gload_lds16(const bf16* g, bf16* l) {
  __builtin_amdgcn_global_load_lds(
      (const __attribute__((address_space(1))) uint32_t*)g,
      (__attribute__((address_space(3))) uint32_t*)l, 16, 0, 0);
}

// ---------------- pack A: f32 row-major (M x K) -> packed bf16 fragments ----------------
// Ap[mb][kb][c(8)][l(64)][8] = A[mb*128 + c*16 + (l&15)][kb*32 + (l>>4)*8 + j]
__global__ __launch_bounds__(256) void pack_a_k(const float* __restrict__ in,
                                                bf16* __restrict__ out,
                                                int K, int nk) {
  int mb = blockIdx.x, kb = blockIdx.y;
  int t = threadIdx.x;
  int c = t >> 5, sub = t & 31;
  bf16* obase = out + (((size_t)mb * nk + kb) * 8 + c) * 512;
#pragma unroll
  for (int i = 0; i < 2; i++) {
    int l = sub * 2 + i;
    int row = mb * 128 + c * 16 + (l & 15);
    int col = kb * 32 + (l >> 4) * 8;
    const float* ip = in + (size_t)row * K + col;
    float4 a = *(const float4*)ip;
    float4 b2 = *(const float4*)(ip + 4);
    bf16x8 o;
    o[0] = (bf16)a.x; o[1] = (bf16)a.y; o[2] = (bf16)a.z; o[3] = (bf16)a.w;
    o[4] = (bf16)b2.x; o[5] = (bf16)b2.y; o[6] = (bf16)b2.z; o[7] = (bf16)b2.w;
    *(bf16x8*)(obase + l * 8) = o;
  }
}

// ---------------- pack B: W f32 row-major (K x N) -> packed bf16 fragments (transposed) ----
// Bp[nb][kb][c(8)][l(64)][8] = W[kb*32 + (l>>4)*8 + j][nb*128 + c*16 + (l&15)]
__global__ __launch_bounds__(256) void pack_b_k(const float* __restrict__ W,
                                                bf16* __restrict__ out,
                                                int N, int nk) {
  __shared__ float ftile[32][132];
  int nb = blockIdx.x, kb = blockIdx.y;
  int t = threadIdx.x;
#pragma unroll
  for (int p = 0; p < 4; p++) {
    int row = p * 8 + (t >> 5);
    int col = (t & 31) * 4;
    float4 v = *(const float4*)(W + (size_t)(kb * 32 + row) * N + nb * 128 + col);
    *(float4*)&ftile[row][col] = v;
  }
  __syncthreads();
  int c = t >> 5, sub = t & 31;
  bf16* obase = out + (((size_t)nb * nk + kb) * 8 + c) * 512;
#pragma unroll
  for (int i = 0; i < 2; i++) {
    int l = sub * 2 + i;
    int rbase = (l >> 4) * 8;
    int coln = c * 16 + (l & 15);
    bf16x8 o;
#pragma unroll
    for (int j = 0; j < 8; j++) o[j] = (bf16)ftile[rbase + j][coln];
    *(bf16x8*)(obase + l * 8) = o;
  }
}

// ---------------- GEMM on packed operands ----------------
// T3/T4: 3-buffer LDS pipeline, depth-2 prefetch, counted s_waitcnt vmcnt(4)
// (never 0 in the main loop) so global_load_lds DMA stays in flight across
// barriers. T5: setprio around the MFMA cluster. T1: XCD-aware bijective
// blockIdx swizzle (both launches use gridDim.x==32, nwg%8==0).
template <typename OutT>
__global__ __launch_bounds__(256, 2) void gemm_p_k(const bf16* __restrict__ Ap,
                                                   const bf16* __restrict__ Bp,
                                                   OutT* __restrict__ C,
                                                   int N, int nk) {
  __shared__ __align__(16) bf16 stage[3][8192];  // 48 KB -> still 3 blocks/CU
  const int t = threadIdx.x;
  const int w = t >> 6, l = t & 63;
  const int quad = l >> 4, ln = l & 15;
  const int wm = w >> 1, wn = w & 1;

  // XCD swizzle: linear dispatch id -> contiguous tile chunk per XCD
  const int nwg = gridDim.x * gridDim.y;
  const int lin = blockIdx.y * gridDim.x + blockIdx.x;
  const int swz = (lin & 7) * (nwg >> 3) + (lin >> 3);
  const int mb = swz & 31;   // gridDim.x == 32 in both gemm launches
  const int nb = swz >> 5;

  // wave w stages chunks gi = 4w..4w+3 (waves 0,1 -> A chunks 0..7; 2,3 -> B chunks 0..7)
  const bf16* sbase = (w < 2 ? Ap + ((size_t)mb * nk * 8 + w * 4) * 512
                             : Bp + ((size_t)nb * nk * 8 + (w - 2) * 4) * 512) + l * 8;

  floatx4 acc[4][4] = {};

  // prologue: stage kb=0 into buf0, kb=1 into buf1 (8 loads/wave in flight)
#pragma unroll
  for (int i = 0; i < 4; i++)
    gload_lds16(sbase + i * 512, stage[0] + w * 2048 + i * 512);
#pragma unroll
  for (int i = 0; i < 4; i++)
    gload_lds16(sbase + 4096 + i * 512, stage[1] + w * 2048 + i * 512);

  int cur = 0;
  for (int kb = 0; kb < nk; kb++) {
    // Wait only for the buffer we are about to consume (oldest 4 loads);
    // the next tile's 4 loads stay in flight across the barrier.
    if (kb + 1 < nk) {
      asm volatile("s_waitcnt vmcnt(4)\n\ts_barrier" ::: "memory");
    } else {
      asm volatile("s_waitcnt vmcnt(0)\n\ts_barrier" ::: "memory");
    }

    // issue prefetch for kb+2 into the buffer consumed at kb-1
    if (kb + 2 < nk) {
      int nxt = cur + 2;
      if (nxt >= 3) nxt -= 3;
      const bf16* s = sbase + (size_t)(kb + 2) * 4096;
      bf16* d = stage[nxt] + w * 2048;
#pragma unroll
      for (int i = 0; i < 4; i++) gload_lds16(s + i * 512, d + i * 512);
    }

    const bf16* curp = stage[cur];
    bf16x8 af[4], bfr[4];
#pragma unroll
    for (int mt = 0; mt < 4; mt++)
      af[mt] = *(const bf16x8*)(curp + (wm * 4 + mt) * 512 + l * 8);
#pragma unroll
    for (int nt = 0; nt < 4; nt++)
      bfr[nt] = *(const bf16x8*)(curp + 4096 + (wn * 4 + nt) * 512 + l * 8);

    __builtin_amdgcn_s_setprio(1);
#pragma unroll
    for (int mt = 0; mt < 4; mt++)
#pragma unroll
      for (int nt = 0; nt < 4; nt++)
        acc[mt][nt] = MFMA16(af[mt], bfr[nt], acc[mt][nt]);
    __builtin_amdgcn_s_setprio(0);

    cur++;
    if (cur == 3) cur = 0;
  }

  const int m0 = mb * 128, n0 = nb * 128;
#pragma unroll
  for (int mt = 0; mt < 4; mt++)
#pragma unroll
    for (int nt = 0; nt < 4; nt++) {
      int row = m0 + wm * 64 + mt * 16 + quad * 4;
      int col = n0 + wn * 64 + nt * 16 + ln;
      OutT* cp = C + (size_t)row * N + col;
#pragma unroll
      for (int r = 0; r < 4; r++)
        cp[(size_t)r * N] = (OutT)acc[mt][nt][r];
    }
}

// ---------------- qkv split + xPos rotary + packed K/V layouts ----------------
__global__ __launch_bounds__(256) void qkv_transform_k(const bf16* __restrict__ qkv,
                                                       const int* __restrict__ pos_ids,
                                                       bf16* __restrict__ Q,
                                                       bf16* __restrict__ Kp,
                                                       bf16* __restrict__ Vp) {
  __shared__ __align__(16) bf16 vtile[128 * 72];
  const float QS = 0.08838834764831845f * LOG2E;  // 1/sqrt(128) * log2(e)
  int blk = blockIdx.x;
  int st = blk & 31;
  int h = (blk >> 5) & 15;
  int b = blk >> 9;
  int bh = b * H_ + h;
  int t = threadIdx.x;
  int sl = t >> 2, dg = t & 3;
  int s = st * 64 + sl;
  float tp = (float)pos_ids[b * S_ + s];

  const bf16* base = qkv + (size_t)(b * S_ + s) * (3 * HID_) + h * (3 * D_) + dg * 32;
  bf16 qv[32], kv[32], vv[32];
#pragma unroll
  for (int i = 0; i < 4; i++) ((bf16x8*)qv)[i] = *(const bf16x8*)(base + i * 8);
#pragma unroll
  for (int i = 0; i < 4; i++) ((bf16x8*)kv)[i] = *(const bf16x8*)(base + D_ + i * 8);
#pragma unroll
  for (int i = 0; i < 4; i++) ((bf16x8*)vv)[i] = *(const bf16x8*)(base + 2 * D_ + i * 8);

  if (dg == 0) {  // rotary covers dims 0..31 exactly
    float power = (tp - 1024.0f) * (1.0f / 512.0f);
#pragma unroll
    for (int i = 0; i < 16; i++) {
      float inv_freq = powf(10000.0f, -(float)i * (1.0f / 16.0f));
      float fr = tp * inv_freq;
      float cs = cosf(fr), sn = sinf(fr);
      float scl = ((float)(2 * i) + 12.8f) * (1.0f / 44.8f);
      float sc = powf(scl, power);
      float cq = cs * sc, sq = sn * sc;
      float ck = cs / sc, sk = sn / sc;
      float q1 = (float)qv[i], q2 = (float)qv[i + 16];
      float k1 = (float)kv[i], k2 = (float)kv[i + 16];
      qv[i] = (bf16)(q1 * cq - q2 * sq);
      qv[i + 16] = (bf16)(q2 * cq + q1 * sq);
      kv[i] = (bf16)(k1 * ck - k2 * sk);
      kv[i + 16] = (bf16)(k2 * ck + k1 * sk);
    }
  }
#pragma unroll
  for (int i = 0; i < 32; i++) qv[i] = (bf16)((float)qv[i] * QS);

  size_t qoff = (size_t)(bh * S_ + s) * D_ + dg * 32;
#pragma unroll
  for (int i = 0; i < 4; i++) *(bf16x8*)(Q + qoff + i * 8) = ((bf16x8*)qv)[i];

  {
    int mt = sl >> 4, lnq = sl & 15;
    bf16* kdst = Kp + (size_t)bh * (S_ * D_) + (size_t)st * 8192 + (mt * 4 + dg) * 512;
#pragma unroll
    for (int q = 0; q < 4; q++)
      *(bf16x8*)(kdst + (q * 16 + lnq) * 8) = ((bf16x8*)kv)[q];
  }

#pragma unroll
  for (int i = 0; i < 32; i++) vtile[(dg * 32 + i) * 72 + sl] = vv[i];
  __syncthreads();

  {
    int c = t >> 4, sub = t & 15;
    int dt = c >> 1, ksv = c & 1;
    bf16* vdst = Vp + (size_t)bh * (S_ * D_) + (size_t)st * 8192 + c * 512;
#pragma unroll
    for (int li = 0; li < 4; li++) {
      int lf = sub * 4 + li;
      int lq = lf >> 4, lln = lf & 15;
      bf16x8 tv = *(const bf16x8*)(vtile + (dt * 16 + lln) * 72 + ksv * 32 + lq * 8);
      *(bf16x8*)(vdst + lf * 8) = tv;
    }
  }
}

// ---------------- flash attention: lockstep waves + dbuf DMA; packed-A output ----------------
__global__ __launch_bounds__(256, 2) void flash_k(const bf16* __restrict__ Q,
                                                  const bf16* __restrict__ Kp,
                                                  const bf16* __restrict__ Vp,
                                                  const float* __restrict__ amask,
                                                  bf16* __restrict__ Ap2) {
  __shared__ __align__(16) bf16 stage[2][16384];
  __shared__ __align__(16) bf16 pbuf[4][16 * 72];
  int blk = blockIdx.x;
  int bh = blk & 31;
  int ab = blk >> 5;
  int b = bh >> 4, h = bh & 15;
  int t = threadIdx.x;
  int w = t >> 6, l = t & 63;
  int quad = l >> 4, ln = l & 15;

  const bf16* Kpb = Kp + (size_t)bh * (S_ * D_);
  const bf16* Vpb = Vp + (size_t)bh * (S_ * D_);
  const float* mbase = amask + (size_t)b * S_;
  bf16* pw = pbuf[w];

#pragma unroll
  for (int j = 0; j < 8; j++) {
    int gi = w * 8 + j;
    const bf16* src = (gi < 16 ? Kpb + gi * 512 : Vpb + (gi - 16) * 512) + l * 8;
    gload_lds16(src, stage[0] + gi * 512);
  }

  int it = 0;
#pragma unroll 1
  for (int phase = 0; phase < 2; phase++) {
    int a = phase ? (31 - ab) : ab;
    int strip = a * 4 + w;
    int qs = strip * 16;
    int T = a + 1;

    const bf16* Qp = Q + (size_t)(bh * S_ + qs + ln) * D_;
    bf16x8 qf[4];
#pragma unroll
    for (int ks = 0; ks < 4; ks++)
      qf[ks] = *(const bf16x8*)(Qp + ks * 32 + quad * 8);

    floatx4 oacc[8] = {};
    float m_i = -1e30f, l_i = 0.f;

#pragma unroll 1
    for (int kt = 0; kt < T; kt++, it++) {
      __syncthreads();
      const bf16* cur = stage[it & 1];
      if (it != 32) {
        int nkv = (kt + 1 < T) ? (kt + 1) : 0;
        bf16* nb = stage[(it + 1) & 1];
#pragma unroll
        for (int j = 0; j < 8; j++) {
          int gi = w * 8 + j;
          const bf16* src = (gi < 16 ? Kpb + (size_t)nkv * 8192 + gi * 512
                                     : Vpb + (size_t)nkv * 8192 + (gi - 16) * 512) + l * 8;
          gload_lds16(src, nb + gi * 512);
        }
      }
      int kv0 = kt * 64;

      floatx4 acc[4] = {};
#pragma unroll
      for (int ks = 0; ks < 4; ks++)
#pragma unroll
        for (int mt = 0; mt < 4; mt++) {
          bf16x8 kf = *(const bf16x8*)(cur + (mt * 4 + ks) * 512 + l * 8);
          acc[mt] = MFMA16(kf, qf[ks], acc[mt]);
        }

      floatx4 am4[4];
#pragma unroll
      for (int mt = 0; mt < 4; mt++)
        am4[mt] = *(const floatx4*)(mbase + kv0 + mt * 16 + quad * 4);

      bool diag = (kt == T - 1);
      int q = qs + ln;
      float v[4][4];
      float mx = -3.0e38f;
#pragma unroll
      for (int mt = 0; mt < 4; mt++)
#pragma unroll
        for (int r = 0; r < 4; r++) {
          float x = acc[mt][r] + am4[mt][r] * LOG2E;
          if (diag && (kv0 + mt * 16 + quad * 4 + r > q)) x = -3.0e38f;
          v[mt][r] = x;
          mx = fmaxf(mx, x);
        }
      mx = fmaxf(mx, __shfl_xor(mx, 16, 64));
      mx = fmaxf(mx, __shfl_xor(mx, 32, 64));
      float mnew = fmaxf(m_i, mx);
      float sum = 0.f;
      bf16x4 pk[4];
#pragma unroll
      for (int mt = 0; mt < 4; mt++)
#pragma unroll
        for (int r = 0; r < 4; r++) {
          float p = exp2f(v[mt][r] - mnew);
          sum += p;
          pk[mt][r] = (bf16)p;
        }
      sum += __shfl_xor(sum, 16, 64);
      sum += __shfl_xor(sum, 32, 64);
      float alpha = exp2f(m_i - mnew);
      l_i = l_i * alpha + sum;
      m_i = mnew;
#pragma unroll
      for (int dt = 0; dt < 8; dt++) oacc[dt] *= alpha;

#pragma unroll
      for (int mt = 0; mt < 4; mt++)
        *(bf16x4*)(pw + ln * 72 + mt * 16 + quad * 4) = pk[mt];

      const bf16* vcur = cur + 8192;
#pragma unroll
      for (int ks = 0; ks < 2; ks++) {
        bf16x8 pf = *(const bf16x8*)(pw + ln * 72 + ks * 32 + quad * 8);
#pragma unroll
        for (int dt = 0; dt < 8; dt++) {
          bf16x8 vf = *(const bf16x8*)(vcur + (dt * 2 + ks) * 512 + l * 8);
          oacc[dt] = MFMA16(vf, pf, oacc[dt]);
        }
      }
    }

    // epilogue: normalize + store directly in gemm2's packed-A layout
    // Ap2[mb][kb][c][l'][8] = attn[mb*128 + c*16 + (l'&15)][kb*32 + (l'>>4)*8 + j]
    float inv_l = 1.0f / l_i;
    int mrow = b * S_ + qs;  // multiple of 16
    int mb2 = mrow >> 7;
    int cc = (mrow >> 4) & 7;
    bf16* abase = Ap2 + ((size_t)mb2 * 64 * 8 + cc) * 512;
#pragma unroll
    for (int dt = 0; dt < 8; dt++) {
      bf16x4 ov;
#pragma unroll
      for (int r = 0; r < 4; r++) ov[r] = (bf16)(oacc[dt][r] * inv_l);
      int kb2 = h * 4 + (dt >> 1);
      int lp = ((dt & 1) * 2 + (quad >> 1)) * 16 + ln;
      *(bf16x4*)(abase + (size_t)kb2 * 4096 + lp * 8 + (quad & 1) * 4) = ov;
    }
  }
}

// ---------------- launch ----------------
extern "C" void kernel_launch(void* const* d_in, const int* in_sizes, int n_in,
                              void* d_out, int out_size, void* d_ws, size_t ws_size,
                              hipStream_t stream) {
  const float* hidden = (const float*)d_in[0];
  const float* amask = (const float*)d_in[1];
  const float* Wqkv = (const float*)d_in[2];
  const float* Wdense = (const float*)d_in[3];
  const int* posids = (const int*)d_in[4];
  float* out = (float*)d_out;
  char* ws = (char*)d_ws;

  // workspace (125,829,120 B, regions reused):
  //  [0,        8.39M)  Bp2 (Wdense packed)           — lives until gemm2
  //  [8.39M,   58.72M)  qkv bf16 (4096 x 6144)        — dead after qkv_transform
  //  [58.72M,  75.50M)  Ap1 (hidden packed) -> Ap2 (attn packed, written by flash)
  //  [75.50M, 100.66M)  Bp1 (Wqkv packed)   -> Q (written by qkv_transform) at 75.50M
  //  [92.27M, 109.05M)  Kp   (over Bp1 tail, written after gemm1)
  //  [109.05M,125.83M)  Vp
  bf16* Bp2 = (bf16*)(ws + 0);
  bf16* qkv = (bf16*)(ws + 8388608ull);
  bf16* Ap1 = (bf16*)(ws + 58720256ull);
  bf16* Ap2 = (bf16*)(ws + 58720256ull);
  bf16* Bp1 = (bf16*)(ws + 75497472ull);
  bf16* Qb = (bf16*)(ws + 75497472ull);
  bf16* Kpb = (bf16*)(ws + 92274688ull);
  bf16* Vpb = (bf16*)(ws + 109051904ull);

  pack_a_k<<<dim3(32, 64), 256, 0, stream>>>(hidden, Ap1, 2048, 64);
  pack_b_k<<<dim3(48, 64), 256, 0, stream>>>(Wqkv, Bp1, 6144, 64);
  pack_b_k<<<dim3(16, 64), 256, 0, stream>>>(Wdense, Bp2, 2048, 64);
  gemm_p_k<bf16><<<dim3(32, 48), 256, 0, stream>>>(Ap1, Bp1, qkv, 6144, 64);
  qkv_transform_k<<<1024, 256, 0, stream>>>(qkv, posids, Qb, Kpb, Vpb);
  flash_k<<<512, 256, 0, stream>>>(Qb, Kpb, Vpb, amask, Ap2);
  gemm_p_k<float><<<dim3(32, 16), 256, 0, stream>>>(Ap2, Bp2, out, 2048, 64);
}

// Round 2
// 389.274 us; speedup vs baseline: 1.0697x; 1.0697x over previous
//
#include <hip/hip_runtime.h>
#include <stdint.h>

#define B_ 2
#define S_ 2048
#define HID_ 2048
#define H_ 16
#define D_ 128
#define LOG2E 1.44269504088896f

typedef __bf16 bf16;
typedef __bf16 bf16x8 __attribute__((ext_vector_type(8)));
typedef __bf16 bf16x4 __attribute__((ext_vector_type(4)));
typedef float floatx4 __attribute__((ext_vector_type(4)));

#define MFMA16(a, b, c) __builtin_amdgcn_mfma_f32_16x16x32_bf16(a, b, c, 0, 0, 0)

__device__ __forceinline__ void gload_lds16(const bf16* g, bf16* l) {
  __builtin_amdgcn_global_load_lds(
      (const __attribute__((address_space(1))) uint32_t*)g,
      (__attribute__((address_space(3))) uint32_t*)l, 16, 0, 0);
}

// ---------------- pack A: f32 row-major (M x K) -> packed bf16 fragments ----------------
// Ap[mb][kb][c(8)][l(64)][8] = A[mb*128 + c*16 + (l&15)][kb*32 + (l>>4)*8 + j]
__global__ __launch_bounds__(256) void pack_a_k(const float* __restrict__ in,
                                                bf16* __restrict__ out,
                                                int K, int nk) {
  int mb = blockIdx.x, kb = blockIdx.y;
  int t = threadIdx.x;
  int c = t >> 5, sub = t & 31;
  bf16* obase = out + (((size_t)mb * nk + kb) * 8 + c) * 512;
#pragma unroll
  for (int i = 0; i < 2; i++) {
    int l = sub * 2 + i;
    int row = mb * 128 + c * 16 + (l & 15);
    int col = kb * 32 + (l >> 4) * 8;
    const float* ip = in + (size_t)row * K + col;
    float4 a = *(const float4*)ip;
    float4 b2 = *(const float4*)(ip + 4);
    bf16x8 o;
    o[0] = (bf16)a.x; o[1] = (bf16)a.y; o[2] = (bf16)a.z; o[3] = (bf16)a.w;
    o[4] = (bf16)b2.x; o[5] = (bf16)b2.y; o[6] = (bf16)b2.z; o[7] = (bf16)b2.w;
    *(bf16x8*)(obase + l * 8) = o;
  }
}

// ---------------- pack B: W f32 row-major (K x N) -> packed bf16 fragments (transposed) ----
// Bp[nb][kb][c(8)][l(64)][8] = W[kb*32 + (l>>4)*8 + j][nb*128 + c*16 + (l&15)]
__global__ __launch_bounds__(256) void pack_b_k(const float* __restrict__ W,
                                                bf16* __restrict__ out,
                                                int N, int nk) {
  __shared__ float ftile[32][132];
  int nb = blockIdx.x, kb = blockIdx.y;
  int t = threadIdx.x;
#pragma unroll
  for (int p = 0; p < 4; p++) {
    int row = p * 8 + (t >> 5);
    int col = (t & 31) * 4;
    float4 v = *(const float4*)(W + (size_t)(kb * 32 + row) * N + nb * 128 + col);
    *(float4*)&ftile[row][col] = v;
  }
  __syncthreads();
  int c = t >> 5, sub = t & 31;
  bf16* obase = out + (((size_t)nb * nk + kb) * 8 + c) * 512;
#pragma unroll
  for (int i = 0; i < 2; i++) {
    int l = sub * 2 + i;
    int rbase = (l >> 4) * 8;
    int coln = c * 16 + (l & 15);
    bf16x8 o;
#pragma unroll
    for (int j = 0; j < 8; j++) o[j] = (bf16)ftile[rbase + j][coln];
    *(bf16x8*)(obase + l * 8) = o;
  }
}

// ---------------- GEMM on packed operands ----------------
// Default blockIdx mapping (round-1 XCD swizzle REVERTED: it exploded the
// per-XCD A working set, FETCH 118->333 MB). Kept: 3-buffer LDS pipeline,
// depth-2 prefetch, counted s_waitcnt vmcnt(4) (never 0 in the main loop),
// setprio around MFMA cluster. Buffer indices are compile-time via
// unroll-by-3 (nk must be 64: 21*3 + 1 tail step).
template <typename OutT>
__global__ __launch_bounds__(256, 2) void gemm_p_k(const bf16* __restrict__ Ap,
                                                   const bf16* __restrict__ Bp,
                                                   OutT* __restrict__ C,
                                                   int N, int nk) {
  __shared__ __align__(16) bf16 stage[3][8192];  // 48 KB -> 3 blocks/CU LDS-wise
  const int t = threadIdx.x;
  const int w = t >> 6, l = t & 63;
  const int quad = l >> 4, ln = l & 15;
  const int wm = w >> 1, wn = w & 1;
  const int mb = blockIdx.x, nb = blockIdx.y;

  // wave w stages chunks gi = 4w..4w+3 (waves 0,1 -> A chunks 0..7; 2,3 -> B chunks 0..7)
  const bf16* sbase = (w < 2 ? Ap + ((size_t)mb * nk * 8 + w * 4) * 512
                             : Bp + ((size_t)nb * nk * 8 + (w - 2) * 4) * 512) + l * 8;

  floatx4 acc[4][4] = {};

  // prologue: stage kb=0 into buf0, kb=1 into buf1 (8 loads/wave in flight)
#pragma unroll
  for (int i = 0; i < 4; i++)
    gload_lds16(sbase + i * 512, stage[0] + w * 2048 + i * 512);
#pragma unroll
  for (int i = 0; i < 4; i++)
    gload_lds16(sbase + 4096 + i * 512, stage[1] + w * 2048 + i * 512);

#define GEMM_STEP(KB, CUR)                                                     \
  {                                                                            \
    if ((KB) + 1 < nk)                                                         \
      asm volatile("s_waitcnt vmcnt(4)\n\ts_barrier" ::: "memory");            \
    else                                                                       \
      asm volatile("s_waitcnt vmcnt(0)\n\ts_barrier" ::: "memory");            \
    if ((KB) + 2 < nk) {                                                       \
      const bf16* s_ = sbase + (size_t)((KB) + 2) * 4096;                      \
      bf16* d_ = stage[((CUR) + 2) % 3] + w * 2048;                            \
      _Pragma("unroll")                                                        \
      for (int i_ = 0; i_ < 4; i_++) gload_lds16(s_ + i_ * 512, d_ + i_ * 512);\
    }                                                                          \
    const bf16* cp_ = stage[(CUR)];                                            \
    bf16x8 af[4], bfr[4];                                                      \
    _Pragma("unroll")                                                          \
    for (int mt = 0; mt < 4; mt++)                                             \
      af[mt] = *(const bf16x8*)(cp_ + (wm * 4 + mt) * 512 + l * 8);            \
    _Pragma("unroll")                                                          \
    for (int nt = 0; nt < 4; nt++)                                             \
      bfr[nt] = *(const bf16x8*)(cp_ + 4096 + (wn * 4 + nt) * 512 + l * 8);    \
    __builtin_amdgcn_s_setprio(1);                                             \
    _Pragma("unroll")                                                          \
    for (int mt = 0; mt < 4; mt++)                                             \
      _Pragma("unroll")                                                        \
      for (int nt = 0; nt < 4; nt++)                                           \
        acc[mt][nt] = MFMA16(af[mt], bfr[nt], acc[mt][nt]);                    \
    __builtin_amdgcn_s_setprio(0);                                             \
  }

#pragma unroll 1
  for (int g = 0; g < 21; g++) {
    int kb = g * 3;
    GEMM_STEP(kb, 0);
    GEMM_STEP(kb + 1, 1);
    GEMM_STEP(kb + 2, 2);
  }
  GEMM_STEP(63, 0);
#undef GEMM_STEP

  const int m0 = mb * 128, n0 = nb * 128;
#pragma unroll
  for (int mt = 0; mt < 4; mt++)
#pragma unroll
    for (int nt = 0; nt < 4; nt++) {
      int row = m0 + wm * 64 + mt * 16 + quad * 4;
      int col = n0 + wn * 64 + nt * 16 + ln;
      OutT* cp = C + (size_t)row * N + col;
#pragma unroll
      for (int r = 0; r < 4; r++)
        cp[(size_t)r * N] = (OutT)acc[mt][nt][r];
    }
}

// ---------------- qkv split + xPos rotary + packed K/V layouts ----------------
__global__ __launch_bounds__(256) void qkv_transform_k(const bf16* __restrict__ qkv,
                                                       const int* __restrict__ pos_ids,
                                                       bf16* __restrict__ Q,
                                                       bf16* __restrict__ Kp,
                                                       bf16* __restrict__ Vp) {
  __shared__ __align__(16) bf16 vtile[128 * 72];
  const float QS = 0.08838834764831845f * LOG2E;  // 1/sqrt(128) * log2(e)
  int blk = blockIdx.x;
  int st = blk & 31;
  int h = (blk >> 5) & 15;
  int b = blk >> 9;
  int bh = b * H_ + h;
  int t = threadIdx.x;
  int sl = t >> 2, dg = t & 3;
  int s = st * 64 + sl;
  float tp = (float)pos_ids[b * S_ + s];

  const bf16* base = qkv + (size_t)(b * S_ + s) * (3 * HID_) + h * (3 * D_) + dg * 32;
  bf16 qv[32], kv[32], vv[32];
#pragma unroll
  for (int i = 0; i < 4; i++) ((bf16x8*)qv)[i] = *(const bf16x8*)(base + i * 8);
#pragma unroll
  for (int i = 0; i < 4; i++) ((bf16x8*)kv)[i] = *(const bf16x8*)(base + D_ + i * 8);
#pragma unroll
  for (int i = 0; i < 4; i++) ((bf16x8*)vv)[i] = *(const bf16x8*)(base + 2 * D_ + i * 8);

  if (dg == 0) {  // rotary covers dims 0..31 exactly
    float power = (tp - 1024.0f) * (1.0f / 512.0f);
#pragma unroll
    for (int i = 0; i < 16; i++) {
      float inv_freq = powf(10000.0f, -(float)i * (1.0f / 16.0f));
      float fr = tp * inv_freq;
      float cs = cosf(fr), sn = sinf(fr);
      float scl = ((float)(2 * i) + 12.8f) * (1.0f / 44.8f);
      float sc = powf(scl, power);
      float cq = cs * sc, sq = sn * sc;
      float ck = cs / sc, sk = sn / sc;
      float q1 = (float)qv[i], q2 = (float)qv[i + 16];
      float k1 = (float)kv[i], k2 = (float)kv[i + 16];
      qv[i] = (bf16)(q1 * cq - q2 * sq);
      qv[i + 16] = (bf16)(q2 * cq + q1 * sq);
      kv[i] = (bf16)(k1 * ck - k2 * sk);
      kv[i + 16] = (bf16)(k2 * ck + k1 * sk);
    }
  }
#pragma unroll
  for (int i = 0; i < 32; i++) qv[i] = (bf16)((float)qv[i] * QS);

  size_t qoff = (size_t)(bh * S_ + s) * D_ + dg * 32;
#pragma unroll
  for (int i = 0; i < 4; i++) *(bf16x8*)(Q + qoff + i * 8) = ((bf16x8*)qv)[i];

  {
    int mt = sl >> 4, lnq = sl & 15;
    bf16* kdst = Kp + (size_t)bh * (S_ * D_) + (size_t)st * 8192 + (mt * 4 + dg) * 512;
#pragma unroll
    for (int q = 0; q < 4; q++)
      *(bf16x8*)(kdst + (q * 16 + lnq) * 8) = ((bf16x8*)kv)[q];
  }

#pragma unroll
  for (int i = 0; i < 32; i++) vtile[(dg * 32 + i) * 72 + sl] = vv[i];
  __syncthreads();

  {
    int c = t >> 4, sub = t & 15;
    int dt = c >> 1, ksv = c & 1;
    bf16* vdst = Vp + (size_t)bh * (S_ * D_) + (size_t)st * 8192 + c * 512;
#pragma unroll
    for (int li = 0; li < 4; li++) {
      int lf = sub * 4 + li;
      int lq = lf >> 4, lln = lf & 15;
      bf16x8 tv = *(const bf16x8*)(vtile + (dt * 16 + lln) * 72 + ksv * 32 + lq * 8);
      *(bf16x8*)(vdst + lf * 8) = tv;
    }
  }
}

// ---------------- flash attention: lockstep waves + dbuf DMA; packed-A output ----------------
// Round-2 change: T13 defer-max (THR=8 in log2 units, __any-guarded) — skip
// the O-rescale + alpha chain when no row's max grew by more than 8.
__global__ __launch_bounds__(256, 2) void flash_k(const bf16* __restrict__ Q,
                                                  const bf16* __restrict__ Kp,
                                                  const bf16* __restrict__ Vp,
                                                  const float* __restrict__ amask,
                                                  bf16* __restrict__ Ap2) {
  __shared__ __align__(16) bf16 stage[2][16384];
  __shared__ __align__(16) bf16 pbuf[4][16 * 72];
  int blk = blockIdx.x;
  int bh = blk & 31;
  int ab = blk >> 5;
  int b = bh >> 4, h = bh & 15;
  int t = threadIdx.x;
  int w = t >> 6, l = t & 63;
  int quad = l >> 4, ln = l & 15;

  const bf16* Kpb = Kp + (size_t)bh * (S_ * D_);
  const bf16* Vpb = Vp + (size_t)bh * (S_ * D_);
  const float* mbase = amask + (size_t)b * S_;
  bf16* pw = pbuf[w];

#pragma unroll
  for (int j = 0; j < 8; j++) {
    int gi = w * 8 + j;
    const bf16* src = (gi < 16 ? Kpb + gi * 512 : Vpb + (gi - 16) * 512) + l * 8;
    gload_lds16(src, stage[0] + gi * 512);
  }

  int it = 0;
#pragma unroll 1
  for (int phase = 0; phase < 2; phase++) {
    int a = phase ? (31 - ab) : ab;
    int strip = a * 4 + w;
    int qs = strip * 16;
    int T = a + 1;

    const bf16* Qp = Q + (size_t)(bh * S_ + qs + ln) * D_;
    bf16x8 qf[4];
#pragma unroll
    for (int ks = 0; ks < 4; ks++)
      qf[ks] = *(const bf16x8*)(Qp + ks * 32 + quad * 8);

    floatx4 oacc[8] = {};
    float m_i = -1e30f, l_i = 0.f;

#pragma unroll 1
    for (int kt = 0; kt < T; kt++, it++) {
      __syncthreads();
      const bf16* cur = stage[it & 1];
      if (it != 32) {
        int nkv = (kt + 1 < T) ? (kt + 1) : 0;
        bf16* nb = stage[(it + 1) & 1];
#pragma unroll
        for (int j = 0; j < 8; j++) {
          int gi = w * 8 + j;
          const bf16* src = (gi < 16 ? Kpb + (size_t)nkv * 8192 + gi * 512
                                     : Vpb + (size_t)nkv * 8192 + (gi - 16) * 512) + l * 8;
          gload_lds16(src, nb + gi * 512);
        }
      }
      int kv0 = kt * 64;

      floatx4 acc[4] = {};
#pragma unroll
      for (int ks = 0; ks < 4; ks++)
#pragma unroll
        for (int mt = 0; mt < 4; mt++) {
          bf16x8 kf = *(const bf16x8*)(cur + (mt * 4 + ks) * 512 + l * 8);
          acc[mt] = MFMA16(kf, qf[ks], acc[mt]);
        }

      floatx4 am4[4];
#pragma unroll
      for (int mt = 0; mt < 4; mt++)
        am4[mt] = *(const floatx4*)(mbase + kv0 + mt * 16 + quad * 4);

      bool diag = (kt == T - 1);
      int q = qs + ln;
      float v[4][4];
      float mx = -3.0e38f;
#pragma unroll
      for (int mt = 0; mt < 4; mt++)
#pragma unroll
        for (int r = 0; r < 4; r++) {
          float x = acc[mt][r] + am4[mt][r] * LOG2E;
          if (diag && (kv0 + mt * 16 + quad * 4 + r > q)) x = -3.0e38f;
          v[mt][r] = x;
          mx = fmaxf(mx, x);
        }
      mx = fmaxf(mx, __shfl_xor(mx, 16, 64));
      mx = fmaxf(mx, __shfl_xor(mx, 32, 64));
      // T13 defer-max: only rescale when some row's max grew by > 8 (log2).
      // When deferred, p <= 2^8 = 256 — fine in bf16/f32 accumulation.
      if (__any(mx > m_i + 8.0f)) {
        float mnew = fmaxf(m_i, mx);
        float alpha = exp2f(m_i - mnew);
        l_i *= alpha;
#pragma unroll
        for (int dt = 0; dt < 8; dt++) oacc[dt] *= alpha;
        m_i = mnew;
      }
      float sum = 0.f;
      bf16x4 pk[4];
#pragma unroll
      for (int mt = 0; mt < 4; mt++)
#pragma unroll
        for (int r = 0; r < 4; r++) {
          float p = exp2f(v[mt][r] - m_i);
          sum += p;
          pk[mt][r] = (bf16)p;
        }
      sum += __shfl_xor(sum, 16, 64);
      sum += __shfl_xor(sum, 32, 64);
      l_i += sum;

#pragma unroll
      for (int mt = 0; mt < 4; mt++)
        *(bf16x4*)(pw + ln * 72 + mt * 16 + quad * 4) = pk[mt];

      const bf16* vcur = cur + 8192;
#pragma unroll
      for (int ks = 0; ks < 2; ks++) {
        bf16x8 pf = *(const bf16x8*)(pw + ln * 72 + ks * 32 + quad * 8);
#pragma unroll
        for (int dt = 0; dt < 8; dt++) {
          bf16x8 vf = *(const bf16x8*)(vcur + (dt * 2 + ks) * 512 + l * 8);
          oacc[dt] = MFMA16(vf, pf, oacc[dt]);
        }
      }
    }

    // epilogue: normalize + store directly in gemm2's packed-A layout
    // Ap2[mb][kb][c][l'][8] = attn[mb*128 + c*16 + (l'&15)][kb*32 + (l'>>4)*8 + j]
    float inv_l = 1.0f / l_i;
    int mrow = b * S_ + qs;  // multiple of 16
    int mb2 = mrow >> 7;
    int cc = (mrow >> 4) & 7;
    bf16* abase = Ap2 + ((size_t)mb2 * 64 * 8 + cc) * 512;
#pragma unroll
    for (int dt = 0; dt < 8; dt++) {
      bf16x4 ov;
#pragma unroll
      for (int r = 0; r < 4; r++) ov[r] = (bf16)(oacc[dt][r] * inv_l);
      int kb2 = h * 4 + (dt >> 1);
      int lp = ((dt & 1) * 2 + (quad >> 1)) * 16 + ln;
      *(bf16x4*)(abase + (size_t)kb2 * 4096 + lp * 8 + (quad & 1) * 4) = ov;
    }
  }
}

// ---------------- launch ----------------
extern "C" void kernel_launch(void* const* d_in, const int* in_sizes, int n_in,
                              void* d_out, int out_size, void* d_ws, size_t ws_size,
                              hipStream_t stream) {
  const float* hidden = (const float*)d_in[0];
  const float* amask = (const float*)d_in[1];
  const float* Wqkv = (const float*)d_in[2];
  const float* Wdense = (const float*)d_in[3];
  const int* posids = (const int*)d_in[4];
  float* out = (float*)d_out;
  char* ws = (char*)d_ws;

  // workspace (125,829,120 B, regions reused):
  //  [0,        8.39M)  Bp2 (Wdense packed)           — lives until gemm2
  //  [8.39M,   58.72M)  qkv bf16 (4096 x 6144)        — dead after qkv_transform
  //  [58.72M,  75.50M)  Ap1 (hidden packed) -> Ap2 (attn packed, written by flash)
  //  [75.50M, 100.66M)  Bp1 (Wqkv packed)   -> Q (written by qkv_transform) at 75.50M
  //  [92.27M, 109.05M)  Kp   (over Bp1 tail, written after gemm1)
  //  [109.05M,125.83M)  Vp
  bf16* Bp2 = (bf16*)(ws + 0);
  bf16* qkv = (bf16*)(ws + 8388608ull);
  bf16* Ap1 = (bf16*)(ws + 58720256ull);
  bf16* Ap2 = (bf16*)(ws + 58720256ull);
  bf16* Bp1 = (bf16*)(ws + 75497472ull);
  bf16* Qb = (bf16*)(ws + 75497472ull);
  bf16* Kpb = (bf16*)(ws + 92274688ull);
  bf16* Vpb = (bf16*)(ws + 109051904ull);

  pack_a_k<<<dim3(32, 64), 256, 0, stream>>>(hidden, Ap1, 2048, 64);
  pack_b_k<<<dim3(48, 64), 256, 0, stream>>>(Wqkv, Bp1, 6144, 64);
  pack_b_k<<<dim3(16, 64), 256, 0, stream>>>(Wdense, Bp2, 2048, 64);
  gemm_p_k<bf16><<<dim3(32, 48), 256, 0, stream>>>(Ap1, Bp1, qkv, 6144, 64);
  qkv_transform_k<<<1024, 256, 0, stream>>>(qkv, posids, Qb, Kpb, Vpb);
  flash_k<<<512, 256, 0, stream>>>(Qb, Kpb, Vpb, amask, Ap2);
  gemm_p_k<float><<<dim3(32, 16), 256, 0, stream>>>(Ap2, Bp2, out, 2048, 64);
}

// Round 3
// 365.606 us; speedup vs baseline: 1.1390x; 1.0647x over previous
//
#include <hip/hip_runtime.h>
#include <stdint.h>

#define B_ 2
#define S_ 2048
#define HID_ 2048
#define H_ 16
#define D_ 128
#define LOG2E 1.44269504088896f

typedef __bf16 bf16;
typedef __bf16 bf16x8 __attribute__((ext_vector_type(8)));
typedef __bf16 bf16x4 __attribute__((ext_vector_type(4)));
typedef float floatx4 __attribute__((ext_vector_type(4)));

#define MFMA16(a, b, c) __builtin_amdgcn_mfma_f32_16x16x32_bf16(a, b, c, 0, 0, 0)

__device__ __forceinline__ void gload_lds16(const bf16* g, bf16* l) {
  __builtin_amdgcn_global_load_lds(
      (const __attribute__((address_space(1))) uint32_t*)g,
      (__attribute__((address_space(3))) uint32_t*)l, 16, 0, 0);
}

// ---------------- pack A: f32 row-major (M x K) -> packed bf16 fragments ----------------
// Ap[mb][kb][c(8)][l(64)][8] = A[mb*128 + c*16 + (l&15)][kb*32 + (l>>4)*8 + j]
__global__ __launch_bounds__(256) void pack_a_k(const float* __restrict__ in,
                                                bf16* __restrict__ out,
                                                int K, int nk) {
  int mb = blockIdx.x, kb = blockIdx.y;
  int t = threadIdx.x;
  int c = t >> 5, sub = t & 31;
  bf16* obase = out + (((size_t)mb * nk + kb) * 8 + c) * 512;
#pragma unroll
  for (int i = 0; i < 2; i++) {
    int l = sub * 2 + i;
    int row = mb * 128 + c * 16 + (l & 15);
    int col = kb * 32 + (l >> 4) * 8;
    const float* ip = in + (size_t)row * K + col;
    float4 a = *(const float4*)ip;
    float4 b2 = *(const float4*)(ip + 4);
    bf16x8 o;
    o[0] = (bf16)a.x; o[1] = (bf16)a.y; o[2] = (bf16)a.z; o[3] = (bf16)a.w;
    o[4] = (bf16)b2.x; o[5] = (bf16)b2.y; o[6] = (bf16)b2.z; o[7] = (bf16)b2.w;
    *(bf16x8*)(obase + l * 8) = o;
  }
}

// ---------------- pack B: W f32 row-major (K x N) -> packed bf16 fragments (transposed) ----
// Bp[nb][kb][c(8)][l(64)][8] = W[kb*32 + (l>>4)*8 + j][nb*128 + c*16 + (l&15)]
__global__ __launch_bounds__(256) void pack_b_k(const float* __restrict__ W,
                                                bf16* __restrict__ out,
                                                int N, int nk) {
  __shared__ float ftile[32][132];
  int nb = blockIdx.x, kb = blockIdx.y;
  int t = threadIdx.x;
#pragma unroll
  for (int p = 0; p < 4; p++) {
    int row = p * 8 + (t >> 5);
    int col = (t & 31) * 4;
    float4 v = *(const float4*)(W + (size_t)(kb * 32 + row) * N + nb * 128 + col);
    *(float4*)&ftile[row][col] = v;
  }
  __syncthreads();
  int c = t >> 5, sub = t & 31;
  bf16* obase = out + (((size_t)nb * nk + kb) * 8 + c) * 512;
#pragma unroll
  for (int i = 0; i < 2; i++) {
    int l = sub * 2 + i;
    int rbase = (l >> 4) * 8;
    int coln = c * 16 + (l & 15);
    bf16x8 o;
#pragma unroll
    for (int j = 0; j < 8; j++) o[j] = (bf16)ftile[rbase + j][coln];
    *(bf16x8*)(obase + l * 8) = o;
  }
}

// ---------------- GEMM on packed operands: dbuf LDS, 1 barrier/iter (round-0 struct) ----
// (round-1/2 counted-vmcnt pipeline graft was measured null -> reverted)
template <typename OutT>
__global__ __launch_bounds__(256, 2) void gemm_p_k(const bf16* __restrict__ Ap,
                                                   const bf16* __restrict__ Bp,
                                                   OutT* __restrict__ C,
                                                   int N, int nk) {
  __shared__ __align__(16) bf16 stage[2][8192];
  const int t = threadIdx.x;
  const int w = t >> 6, l = t & 63;
  const int quad = l >> 4, ln = l & 15;
  const int wm = w >> 1, wn = w & 1;
  const int mb = blockIdx.x, nb = blockIdx.y;

  const bf16* sbase = (w < 2 ? Ap + ((size_t)mb * nk * 8 + w * 4) * 512
                             : Bp + ((size_t)nb * nk * 8 + (w - 2) * 4) * 512) + l * 8;
  bf16* dbase0 = stage[0] + w * 2048;
  bf16* dbase1 = stage[1] + w * 2048;

  floatx4 acc[4][4] = {};

#pragma unroll
  for (int i = 0; i < 4; i++) gload_lds16(sbase + i * 512, dbase0 + i * 512);

  for (int kb = 0; kb < nk; kb++) {
    __syncthreads();
    if (kb + 1 < nk) {
      const bf16* s = sbase + (size_t)(kb + 1) * 4096;
      bf16* d = ((kb + 1) & 1) ? dbase1 : dbase0;
#pragma unroll
      for (int i = 0; i < 4; i++) gload_lds16(s + i * 512, d + i * 512);
    }
    const bf16* cur = stage[kb & 1];
    bf16x8 af[4], bfr[4];
#pragma unroll
    for (int mt = 0; mt < 4; mt++)
      af[mt] = *(const bf16x8*)(cur + (wm * 4 + mt) * 512 + l * 8);
#pragma unroll
    for (int nt = 0; nt < 4; nt++)
      bfr[nt] = *(const bf16x8*)(cur + 4096 + (wn * 4 + nt) * 512 + l * 8);
#pragma unroll
    for (int mt = 0; mt < 4; mt++)
#pragma unroll
      for (int nt = 0; nt < 4; nt++)
        acc[mt][nt] = MFMA16(af[mt], bfr[nt], acc[mt][nt]);
  }

  const int m0 = mb * 128, n0 = nb * 128;
#pragma unroll
  for (int mt = 0; mt < 4; mt++)
#pragma unroll
    for (int nt = 0; nt < 4; nt++) {
      int row = m0 + wm * 64 + mt * 16 + quad * 4;
      int col = n0 + wn * 64 + nt * 16 + ln;
      OutT* cp = C + (size_t)row * N + col;
#pragma unroll
      for (int r = 0; r < 4; r++)
        cp[(size_t)r * N] = (OutT)acc[mt][nt][r];
    }
}

// ---------------- fused QKV GEMM: rotary + scale + Q/Kp/Vp scatter in epilogue ----------
// Replaces gemm1 + qkv_transform (saves ~100 MB HBM round-trip + one dispatch).
// nb tile type: nb%3 == 0 -> Q dims [0,128) of head nb/3; ==1 -> K; ==2 -> V.
// Rotary pairs (i, i+16), i=ln, live in the same thread (nt=0 vs nt=1).
__global__ __launch_bounds__(256, 2) void gemm_qkv_k(const bf16* __restrict__ Ap,
                                                     const bf16* __restrict__ Bp,
                                                     const int* __restrict__ pos_ids,
                                                     bf16* __restrict__ Q,
                                                     bf16* __restrict__ Kp,
                                                     bf16* __restrict__ Vp,
                                                     int nk) {
  __shared__ __align__(16) bf16 stage[2][8192];
  const int t = threadIdx.x;
  const int w = t >> 6, l = t & 63;
  const int quad = l >> 4, ln = l & 15;
  const int wm = w >> 1, wn = w & 1;
  const int mb = blockIdx.x, nb = blockIdx.y;

  const bf16* sbase = (w < 2 ? Ap + ((size_t)mb * nk * 8 + w * 4) * 512
                             : Bp + ((size_t)nb * nk * 8 + (w - 2) * 4) * 512) + l * 8;
  bf16* dbase0 = stage[0] + w * 2048;
  bf16* dbase1 = stage[1] + w * 2048;

  floatx4 acc[4][4] = {};

#pragma unroll
  for (int i = 0; i < 4; i++) gload_lds16(sbase + i * 512, dbase0 + i * 512);

  for (int kb = 0; kb < nk; kb++) {
    __syncthreads();
    if (kb + 1 < nk) {
      const bf16* s = sbase + (size_t)(kb + 1) * 4096;
      bf16* d = ((kb + 1) & 1) ? dbase1 : dbase0;
#pragma unroll
      for (int i = 0; i < 4; i++) gload_lds16(s + i * 512, d + i * 512);
    }
    const bf16* cur = stage[kb & 1];
    bf16x8 af[4], bfr[4];
#pragma unroll
    for (int mt = 0; mt < 4; mt++)
      af[mt] = *(const bf16x8*)(cur + (wm * 4 + mt) * 512 + l * 8);
#pragma unroll
    for (int nt = 0; nt < 4; nt++)
      bfr[nt] = *(const bf16x8*)(cur + 4096 + (wn * 4 + nt) * 512 + l * 8);
#pragma unroll
    for (int mt = 0; mt < 4; mt++)
#pragma unroll
      for (int nt = 0; nt < 4; nt++)
        acc[mt][nt] = MFMA16(af[mt], bfr[nt], acc[mt][nt]);
  }

  // ---- epilogue: this thread holds acc[mt][nt][r] = val at
  //      row = mb*128 + wm*64 + mt*16 + quad*4 + r   (b = row>>11, s = row&2047)
  //      d   = wn*64 + nt*16 + ln                    (head dim 0..127)
  const int h = nb / 3;
  const int type = nb - h * 3;
  const int m0 = mb * 128;

  if (type == 2) {
    // V -> packed Vp[bh][s>>6][c][lf][j]: c=(d>>4)*2+((s>>5)&1),
    // lf=(((s>>3)&3))*16+(d&15), j=s&7.  r maps to consecutive j -> bf16x4.
#pragma unroll
    for (int mt = 0; mt < 4; mt++) {
      int row0 = m0 + wm * 64 + mt * 16 + quad * 4;
      int b = row0 >> 11, s0 = row0 & 2047;
      size_t vb = (size_t)(b * 16 + h) * (S_ * D_) + (size_t)(s0 >> 6) * 8192;
      int lf = ((mt & 1) * 2 + (quad >> 1)) * 16 + ln;
      int j0 = (quad & 1) * 4;
#pragma unroll
      for (int nt = 0; nt < 4; nt++) {
        int cv = (wn * 4 + nt) * 2 + (mt >> 1);
        bf16x4 ov;
#pragma unroll
        for (int r = 0; r < 4; r++) ov[r] = (bf16)acc[mt][nt][r];
        *(bf16x4*)(Vp + vb + cv * 512 + lf * 8 + j0) = ov;
      }
    }
    return;
  }

  if (wn == 0) {  // rotary covers dims 0..31 = (nt=0, nt=1) pairs; wave-uniform branch
    float invf = powf(10000.f, -(float)ln * (1.f / 16.f));
    float l2scl = log2f(((float)(2 * ln) + 12.8f) * (1.f / 44.8f));
#pragma unroll
    for (int mt = 0; mt < 4; mt++)
#pragma unroll
      for (int r = 0; r < 4; r++) {
        int row = m0 + wm * 64 + mt * 16 + quad * 4 + r;
        float tp = (float)pos_ids[row];
        float fr = tp * invf;
        float cs = cosf(fr), sn = sinf(fr);
        float sc = exp2f(l2scl * (tp - 1024.f) * (1.f / 512.f));
        float c_, s_;
        if (type == 0) { c_ = cs * sc; s_ = sn * sc; }
        else           { c_ = cs / sc; s_ = sn / sc; }
        float x1 = acc[mt][0][r], x2 = acc[mt][1][r];
        acc[mt][0][r] = x1 * c_ - x2 * s_;
        acc[mt][1][r] = x2 * c_ + x1 * s_;
      }
  }

  if (type == 0) {
    // Q row-major [bh][s][d], pre-scaled by 1/sqrt(D)*log2(e)
    const float QS = 0.08838834764831845f * LOG2E;
#pragma unroll
    for (int mt = 0; mt < 4; mt++) {
      int row0 = m0 + wm * 64 + mt * 16 + quad * 4;
      int b = row0 >> 11, s0 = row0 & 2047;
      bf16* qb = Q + ((size_t)(b * 16 + h) * S_ + s0) * D_ + wn * 64 + ln;
#pragma unroll
      for (int nt = 0; nt < 4; nt++)
#pragma unroll
        for (int r = 0; r < 4; r++)
          qb[(size_t)r * D_ + nt * 16] = (bf16)(acc[mt][nt][r] * QS);
    }
  } else {
    // K -> packed Kp[bh][s>>6][c][l'][j]: c=((s>>4)&3)*4+(d>>5),
    // l'=((d>>3)&3)*16+(s&15), j=d&7
#pragma unroll
    for (int mt = 0; mt < 4; mt++) {
      int row0 = m0 + wm * 64 + mt * 16 + quad * 4;
      int b = row0 >> 11, s0 = row0 & 2047;
      bf16* kb_ = Kp + (size_t)(b * 16 + h) * (S_ * D_) + (size_t)(s0 >> 6) * 8192 + (ln & 7);
#pragma unroll
      for (int nt = 0; nt < 4; nt++) {
        int ck = mt * 4 + wn * 2 + (nt >> 1);
        int lp = ((nt & 1) * 2 + (ln >> 3)) * 16 + quad * 4;
#pragma unroll
        for (int r = 0; r < 4; r++)
          kb_[ck * 512 + (lp + r) * 8] = (bf16)acc[mt][nt][r];
      }
    }
  }
}

// ---------------- flash attention: lockstep waves + dbuf DMA; packed-A output ----------------
__global__ __launch_bounds__(256, 2) void flash_k(const bf16* __restrict__ Q,
                                                  const bf16* __restrict__ Kp,
                                                  const bf16* __restrict__ Vp,
                                                  const float* __restrict__ amask,
                                                  bf16* __restrict__ Ap2) {
  __shared__ __align__(16) bf16 stage[2][16384];
  __shared__ __align__(16) bf16 pbuf[4][16 * 72];
  int blk = blockIdx.x;
  int bh = blk & 31;
  int ab = blk >> 5;
  int b = bh >> 4, h = bh & 15;
  int t = threadIdx.x;
  int w = t >> 6, l = t & 63;
  int quad = l >> 4, ln = l & 15;

  const bf16* Kpb = Kp + (size_t)bh * (S_ * D_);
  const bf16* Vpb = Vp + (size_t)bh * (S_ * D_);
  const float* mbase = amask + (size_t)b * S_;
  bf16* pw = pbuf[w];

#pragma unroll
  for (int j = 0; j < 8; j++) {
    int gi = w * 8 + j;
    const bf16* src = (gi < 16 ? Kpb + gi * 512 : Vpb + (gi - 16) * 512) + l * 8;
    gload_lds16(src, stage[0] + gi * 512);
  }

  int it = 0;
#pragma unroll 1
  for (int phase = 0; phase < 2; phase++) {
    int a = phase ? (31 - ab) : ab;
    int strip = a * 4 + w;
    int qs = strip * 16;
    int T = a + 1;

    const bf16* Qp = Q + (size_t)(bh * S_ + qs + ln) * D_;
    bf16x8 qf[4];
#pragma unroll
    for (int ks = 0; ks < 4; ks++)
      qf[ks] = *(const bf16x8*)(Qp + ks * 32 + quad * 8);

    floatx4 oacc[8] = {};
    float m_i = -1e30f, l_i = 0.f;

#pragma unroll 1
    for (int kt = 0; kt < T; kt++, it++) {
      __syncthreads();
      const bf16* cur = stage[it & 1];
      if (it != 32) {
        int nkv = (kt + 1 < T) ? (kt + 1) : 0;
        bf16* nb = stage[(it + 1) & 1];
#pragma unroll
        for (int j = 0; j < 8; j++) {
          int gi = w * 8 + j;
          const bf16* src = (gi < 16 ? Kpb + (size_t)nkv * 8192 + gi * 512
                                     : Vpb + (size_t)nkv * 8192 + (gi - 16) * 512) + l * 8;
          gload_lds16(src, nb + gi * 512);
        }
      }
      int kv0 = kt * 64;

      floatx4 acc[4] = {};
#pragma unroll
      for (int ks = 0; ks < 4; ks++)
#pragma unroll
        for (int mt = 0; mt < 4; mt++) {
          bf16x8 kf = *(const bf16x8*)(cur + (mt * 4 + ks) * 512 + l * 8);
          acc[mt] = MFMA16(kf, qf[ks], acc[mt]);
        }

      floatx4 am4[4];
#pragma unroll
      for (int mt = 0; mt < 4; mt++)
        am4[mt] = *(const floatx4*)(mbase + kv0 + mt * 16 + quad * 4);

      bool diag = (kt == T - 1);
      int q = qs + ln;
      float v[4][4];
      float mx = -3.0e38f;
#pragma unroll
      for (int mt = 0; mt < 4; mt++)
#pragma unroll
        for (int r = 0; r < 4; r++) {
          float x = acc[mt][r] + am4[mt][r] * LOG2E;
          if (diag && (kv0 + mt * 16 + quad * 4 + r > q)) x = -3.0e38f;
          v[mt][r] = x;
          mx = fmaxf(mx, x);
        }
      mx = fmaxf(mx, __shfl_xor(mx, 16, 64));
      mx = fmaxf(mx, __shfl_xor(mx, 32, 64));
      // T13 defer-max: only rescale when some row's max grew by > 8 (log2).
      if (__any(mx > m_i + 8.0f)) {
        float mnew = fmaxf(m_i, mx);
        float alpha = exp2f(m_i - mnew);
        l_i *= alpha;
#pragma unroll
        for (int dt = 0; dt < 8; dt++) oacc[dt] *= alpha;
        m_i = mnew;
      }
      float sum = 0.f;
      bf16x4 pk[4];
#pragma unroll
      for (int mt = 0; mt < 4; mt++)
#pragma unroll
        for (int r = 0; r < 4; r++) {
          float p = exp2f(v[mt][r] - m_i);
          sum += p;
          pk[mt][r] = (bf16)p;
        }
      sum += __shfl_xor(sum, 16, 64);
      sum += __shfl_xor(sum, 32, 64);
      l_i += sum;

#pragma unroll
      for (int mt = 0; mt < 4; mt++)
        *(bf16x4*)(pw + ln * 72 + mt * 16 + quad * 4) = pk[mt];

      const bf16* vcur = cur + 8192;
#pragma unroll
      for (int ks = 0; ks < 2; ks++) {
        bf16x8 pf = *(const bf16x8*)(pw + ln * 72 + ks * 32 + quad * 8);
#pragma unroll
        for (int dt = 0; dt < 8; dt++) {
          bf16x8 vf = *(const bf16x8*)(vcur + (dt * 2 + ks) * 512 + l * 8);
          oacc[dt] = MFMA16(vf, pf, oacc[dt]);
        }
      }
    }

    // epilogue: normalize + store directly in gemm2's packed-A layout
    float inv_l = 1.0f / l_i;
    int mrow = b * S_ + qs;  // multiple of 16
    int mb2 = mrow >> 7;
    int cc = (mrow >> 4) & 7;
    bf16* abase = Ap2 + ((size_t)mb2 * 64 * 8 + cc) * 512;
#pragma unroll
    for (int dt = 0; dt < 8; dt++) {
      bf16x4 ov;
#pragma unroll
      for (int r = 0; r < 4; r++) ov[r] = (bf16)(oacc[dt][r] * inv_l);
      int kb2 = h * 4 + (dt >> 1);
      int lp = ((dt & 1) * 2 + (quad >> 1)) * 16 + ln;
      *(bf16x4*)(abase + (size_t)kb2 * 4096 + lp * 8 + (quad & 1) * 4) = ov;
    }
  }
}

// ---------------- launch ----------------
extern "C" void kernel_launch(void* const* d_in, const int* in_sizes, int n_in,
                              void* d_out, int out_size, void* d_ws, size_t ws_size,
                              hipStream_t stream) {
  const float* hidden = (const float*)d_in[0];
  const float* amask = (const float*)d_in[1];
  const float* Wqkv = (const float*)d_in[2];
  const float* Wdense = (const float*)d_in[3];
  const int* posids = (const int*)d_in[4];
  float* out = (float*)d_out;
  char* ws = (char*)d_ws;

  // workspace layout (100.7 MB of the 125.8 MB used; all live ranges disjoint):
  //  [0,        8.39M)  Bp2 (Wdense packed)       — lives until gemm2
  //  [8.39M,  25.17M)  Ap1 (hidden packed) -> Ap2 (attn packed, written by flash)
  //  [25.17M, 50.33M)  Bp1 (Wqkv packed)          — read by gemm_qkv
  //  [50.33M, 67.11M)  Q   (written by gemm_qkv epilogue)
  //  [67.11M, 83.89M)  Kp
  //  [83.89M,100.66M)  Vp
  bf16* Bp2 = (bf16*)(ws + 0);
  bf16* Ap1 = (bf16*)(ws + 8388608ull);
  bf16* Ap2 = (bf16*)(ws + 8388608ull);
  bf16* Bp1 = (bf16*)(ws + 25165824ull);
  bf16* Qb = (bf16*)(ws + 50331648ull);
  bf16* Kpb = (bf16*)(ws + 67108864ull);
  bf16* Vpb = (bf16*)(ws + 83886080ull);

  pack_a_k<<<dim3(32, 64), 256, 0, stream>>>(hidden, Ap1, 2048, 64);
  pack_b_k<<<dim3(48, 64), 256, 0, stream>>>(Wqkv, Bp1, 6144, 64);
  pack_b_k<<<dim3(16, 64), 256, 0, stream>>>(Wdense, Bp2, 2048, 64);
  gemm_qkv_k<<<dim3(32, 48), 256, 0, stream>>>(Ap1, Bp1, posids, Qb, Kpb, Vpb, 64);
  flash_k<<<512, 256, 0, stream>>>(Qb, Kpb, Vpb, amask, Ap2);
  gemm_p_k<float><<<dim3(32, 16), 256, 0, stream>>>(Ap2, Bp2, out, 2048, 64);
}

// Round 4
// 361.126 us; speedup vs baseline: 1.1531x; 1.0124x over previous
//
#include <hip/hip_runtime.h>
#include <stdint.h>

#define B_ 2
#define S_ 2048
#define HID_ 2048
#define H_ 16
#define D_ 128
#define LOG2E 1.44269504088896f

typedef __bf16 bf16;
typedef __bf16 bf16x8 __attribute__((ext_vector_type(8)));
typedef __bf16 bf16x4 __attribute__((ext_vector_type(4)));
typedef float floatx4 __attribute__((ext_vector_type(4)));

#define MFMA16(a, b, c) __builtin_amdgcn_mfma_f32_16x16x32_bf16(a, b, c, 0, 0, 0)

__device__ __forceinline__ void gload_lds16(const bf16* g, bf16* l) {
  __builtin_amdgcn_global_load_lds(
      (const __attribute__((address_space(1))) uint32_t*)g,
      (__attribute__((address_space(3))) uint32_t*)l, 16, 0, 0);
}

// ---------------- rotary coefficient LUT: lut[row*16+i] = {cq, sq, ck, sk} ------------
// Hoists all epilogue transcendentals (round-3 post-mortem: +17 us VALU tail in
// gemm_qkv) into one tiny dispatch. 4096 rows x 16 freqs x 16 B = 1 MB, L2/L3-resident.
__global__ __launch_bounds__(256) void rotlut_k(const int* __restrict__ pos_ids,
                                                float4* __restrict__ lut) {
  int idx = blockIdx.x * 256 + threadIdx.x;  // idx = row*16 + i
  int row = idx >> 4, i = idx & 15;
  float tp = (float)pos_ids[row];
  float invf = powf(10000.f, -(float)i * (1.f / 16.f));
  float fr = tp * invf;
  float cs = cosf(fr), sn = sinf(fr);
  float scl = ((float)(2 * i) + 12.8f) * (1.f / 44.8f);
  float sc = powf(scl, (tp - 1024.f) * (1.f / 512.f));
  float4 o;
  o.x = cs * sc;
  o.y = sn * sc;
  o.z = cs / sc;
  o.w = sn / sc;
  lut[idx] = o;
}

// ---------------- pack A: f32 row-major (M x K) -> packed bf16 fragments ----------------
// Ap[mb][kb][c(8)][l(64)][8] = A[mb*128 + c*16 + (l&15)][kb*32 + (l>>4)*8 + j]
__global__ __launch_bounds__(256) void pack_a_k(const float* __restrict__ in,
                                                bf16* __restrict__ out,
                                                int K, int nk) {
  int mb = blockIdx.x, kb = blockIdx.y;
  int t = threadIdx.x;
  int c = t >> 5, sub = t & 31;
  bf16* obase = out + (((size_t)mb * nk + kb) * 8 + c) * 512;
#pragma unroll
  for (int i = 0; i < 2; i++) {
    int l = sub * 2 + i;
    int row = mb * 128 + c * 16 + (l & 15);
    int col = kb * 32 + (l >> 4) * 8;
    const float* ip = in + (size_t)row * K + col;
    float4 a = *(const float4*)ip;
    float4 b2 = *(const float4*)(ip + 4);
    bf16x8 o;
    o[0] = (bf16)a.x; o[1] = (bf16)a.y; o[2] = (bf16)a.z; o[3] = (bf16)a.w;
    o[4] = (bf16)b2.x; o[5] = (bf16)b2.y; o[6] = (bf16)b2.z; o[7] = (bf16)b2.w;
    *(bf16x8*)(obase + l * 8) = o;
  }
}

// ---------------- pack B: W f32 row-major (K x N) -> packed bf16 fragments (transposed) ----
// Bp[nb][kb][c(8)][l(64)][8] = W[kb*32 + (l>>4)*8 + j][nb*128 + c*16 + (l&15)]
__global__ __launch_bounds__(256) void pack_b_k(const float* __restrict__ W,
                                                bf16* __restrict__ out,
                                                int N, int nk) {
  __shared__ float ftile[32][132];
  int nb = blockIdx.x, kb = blockIdx.y;
  int t = threadIdx.x;
#pragma unroll
  for (int p = 0; p < 4; p++) {
    int row = p * 8 + (t >> 5);
    int col = (t & 31) * 4;
    float4 v = *(const float4*)(W + (size_t)(kb * 32 + row) * N + nb * 128 + col);
    *(float4*)&ftile[row][col] = v;
  }
  __syncthreads();
  int c = t >> 5, sub = t & 31;
  bf16* obase = out + (((size_t)nb * nk + kb) * 8 + c) * 512;
#pragma unroll
  for (int i = 0; i < 2; i++) {
    int l = sub * 2 + i;
    int rbase = (l >> 4) * 8;
    int coln = c * 16 + (l & 15);
    bf16x8 o;
#pragma unroll
    for (int j = 0; j < 8; j++) o[j] = (bf16)ftile[rbase + j][coln];
    *(bf16x8*)(obase + l * 8) = o;
  }
}

// ---------------- GEMM on packed operands: dbuf LDS, 1 barrier/iter (round-0 struct) ----
template <typename OutT>
__global__ __launch_bounds__(256, 2) void gemm_p_k(const bf16* __restrict__ Ap,
                                                   const bf16* __restrict__ Bp,
                                                   OutT* __restrict__ C,
                                                   int N, int nk) {
  __shared__ __align__(16) bf16 stage[2][8192];
  const int t = threadIdx.x;
  const int w = t >> 6, l = t & 63;
  const int quad = l >> 4, ln = l & 15;
  const int wm = w >> 1, wn = w & 1;
  const int mb = blockIdx.x, nb = blockIdx.y;

  const bf16* sbase = (w < 2 ? Ap + ((size_t)mb * nk * 8 + w * 4) * 512
                             : Bp + ((size_t)nb * nk * 8 + (w - 2) * 4) * 512) + l * 8;
  bf16* dbase0 = stage[0] + w * 2048;
  bf16* dbase1 = stage[1] + w * 2048;

  floatx4 acc[4][4] = {};

#pragma unroll
  for (int i = 0; i < 4; i++) gload_lds16(sbase + i * 512, dbase0 + i * 512);

  for (int kb = 0; kb < nk; kb++) {
    __syncthreads();
    if (kb + 1 < nk) {
      const bf16* s = sbase + (size_t)(kb + 1) * 4096;
      bf16* d = ((kb + 1) & 1) ? dbase1 : dbase0;
#pragma unroll
      for (int i = 0; i < 4; i++) gload_lds16(s + i * 512, d + i * 512);
    }
    const bf16* cur = stage[kb & 1];
    bf16x8 af[4], bfr[4];
#pragma unroll
    for (int mt = 0; mt < 4; mt++)
      af[mt] = *(const bf16x8*)(cur + (wm * 4 + mt) * 512 + l * 8);
#pragma unroll
    for (int nt = 0; nt < 4; nt++)
      bfr[nt] = *(const bf16x8*)(cur + 4096 + (wn * 4 + nt) * 512 + l * 8);
#pragma unroll
    for (int mt = 0; mt < 4; mt++)
#pragma unroll
      for (int nt = 0; nt < 4; nt++)
        acc[mt][nt] = MFMA16(af[mt], bfr[nt], acc[mt][nt]);
  }

  const int m0 = mb * 128, n0 = nb * 128;
#pragma unroll
  for (int mt = 0; mt < 4; mt++)
#pragma unroll
    for (int nt = 0; nt < 4; nt++) {
      int row = m0 + wm * 64 + mt * 16 + quad * 4;
      int col = n0 + wn * 64 + nt * 16 + ln;
      OutT* cp = C + (size_t)row * N + col;
#pragma unroll
      for (int r = 0; r < 4; r++)
        cp[(size_t)r * N] = (OutT)acc[mt][nt][r];
    }
}

// ---------------- fused QKV GEMM: rotary (via LUT) + scale + Q/Kp/Vp scatter ----------
// nb tile type: nb%3 == 0 -> Q dims [0,128) of head nb/3; ==1 -> K; ==2 -> V.
// Rotary pairs (i, i+16), i=ln, live in the same thread (nt=0 vs nt=1).
__global__ __launch_bounds__(256, 2) void gemm_qkv_k(const bf16* __restrict__ Ap,
                                                     const bf16* __restrict__ Bp,
                                                     const float4* __restrict__ lut,
                                                     bf16* __restrict__ Q,
                                                     bf16* __restrict__ Kp,
                                                     bf16* __restrict__ Vp,
                                                     int nk) {
  __shared__ __align__(16) bf16 stage[2][8192];
  const int t = threadIdx.x;
  const int w = t >> 6, l = t & 63;
  const int quad = l >> 4, ln = l & 15;
  const int wm = w >> 1, wn = w & 1;
  const int mb = blockIdx.x, nb = blockIdx.y;

  const bf16* sbase = (w < 2 ? Ap + ((size_t)mb * nk * 8 + w * 4) * 512
                             : Bp + ((size_t)nb * nk * 8 + (w - 2) * 4) * 512) + l * 8;
  bf16* dbase0 = stage[0] + w * 2048;
  bf16* dbase1 = stage[1] + w * 2048;

  floatx4 acc[4][4] = {};

#pragma unroll
  for (int i = 0; i < 4; i++) gload_lds16(sbase + i * 512, dbase0 + i * 512);

  for (int kb = 0; kb < nk; kb++) {
    __syncthreads();
    if (kb + 1 < nk) {
      const bf16* s = sbase + (size_t)(kb + 1) * 4096;
      bf16* d = ((kb + 1) & 1) ? dbase1 : dbase0;
#pragma unroll
      for (int i = 0; i < 4; i++) gload_lds16(s + i * 512, d + i * 512);
    }
    const bf16* cur = stage[kb & 1];
    bf16x8 af[4], bfr[4];
#pragma unroll
    for (int mt = 0; mt < 4; mt++)
      af[mt] = *(const bf16x8*)(cur + (wm * 4 + mt) * 512 + l * 8);
#pragma unroll
    for (int nt = 0; nt < 4; nt++)
      bfr[nt] = *(const bf16x8*)(cur + 4096 + (wn * 4 + nt) * 512 + l * 8);
#pragma unroll
    for (int mt = 0; mt < 4; mt++)
#pragma unroll
      for (int nt = 0; nt < 4; nt++)
        acc[mt][nt] = MFMA16(af[mt], bfr[nt], acc[mt][nt]);
  }

  // ---- epilogue: this thread holds acc[mt][nt][r] = val at
  //      row = mb*128 + wm*64 + mt*16 + quad*4 + r   (b = row>>11, s = row&2047)
  //      d   = wn*64 + nt*16 + ln                    (head dim 0..127)
  const int h = nb / 3;
  const int type = nb - h * 3;
  const int m0 = mb * 128;

  if (type == 2) {
    // V -> packed Vp[bh][s>>6][c][lf][j]: c=(d>>4)*2+((s>>5)&1),
    // lf=(((s>>3)&3))*16+(d&15), j=s&7.  r maps to consecutive j -> bf16x4.
#pragma unroll
    for (int mt = 0; mt < 4; mt++) {
      int row0 = m0 + wm * 64 + mt * 16 + quad * 4;
      int b = row0 >> 11, s0 = row0 & 2047;
      size_t vb = (size_t)(b * 16 + h) * (S_ * D_) + (size_t)(s0 >> 6) * 8192;
      int lf = ((mt & 1) * 2 + (quad >> 1)) * 16 + ln;
      int j0 = (quad & 1) * 4;
#pragma unroll
      for (int nt = 0; nt < 4; nt++) {
        int cv = (wn * 4 + nt) * 2 + (mt >> 1);
        bf16x4 ov;
#pragma unroll
        for (int r = 0; r < 4; r++) ov[r] = (bf16)acc[mt][nt][r];
        *(bf16x4*)(Vp + vb + cv * 512 + lf * 8 + j0) = ov;
      }
    }
    return;
  }

  if (wn == 0) {  // rotary covers dims 0..31 = (nt=0, nt=1) pairs; wave-uniform branch
#pragma unroll
    for (int mt = 0; mt < 4; mt++)
#pragma unroll
      for (int r = 0; r < 4; r++) {
        int row = m0 + wm * 64 + mt * 16 + quad * 4 + r;
        float4 cf = lut[row * 16 + ln];
        float c_ = (type == 0) ? cf.x : cf.z;
        float s_ = (type == 0) ? cf.y : cf.w;
        float x1 = acc[mt][0][r], x2 = acc[mt][1][r];
        acc[mt][0][r] = x1 * c_ - x2 * s_;
        acc[mt][1][r] = x2 * c_ + x1 * s_;
      }
  }

  if (type == 0) {
    // Q row-major [bh][s][d], pre-scaled by 1/sqrt(D)*log2(e)
    const float QS = 0.08838834764831845f * LOG2E;
#pragma unroll
    for (int mt = 0; mt < 4; mt++) {
      int row0 = m0 + wm * 64 + mt * 16 + quad * 4;
      int b = row0 >> 11, s0 = row0 & 2047;
      bf16* qb = Q + ((size_t)(b * 16 + h) * S_ + s0) * D_ + wn * 64 + ln;
#pragma unroll
      for (int nt = 0; nt < 4; nt++)
#pragma unroll
        for (int r = 0; r < 4; r++)
          qb[(size_t)r * D_ + nt * 16] = (bf16)(acc[mt][nt][r] * QS);
    }
  } else {
    // K -> packed Kp[bh][s>>6][c][l'][j]: c=((s>>4)&3)*4+(d>>5),
    // l'=((d>>3)&3)*16+(s&15), j=d&7
#pragma unroll
    for (int mt = 0; mt < 4; mt++) {
      int row0 = m0 + wm * 64 + mt * 16 + quad * 4;
      int b = row0 >> 11, s0 = row0 & 2047;
      bf16* kb_ = Kp + (size_t)(b * 16 + h) * (S_ * D_) + (size_t)(s0 >> 6) * 8192 + (ln & 7);
#pragma unroll
      for (int nt = 0; nt < 4; nt++) {
        int ck = mt * 4 + wn * 2 + (nt >> 1);
        int lp = ((nt & 1) * 2 + (ln >> 3)) * 16 + quad * 4;
#pragma unroll
        for (int r = 0; r < 4; r++)
          kb_[ck * 512 + (lp + r) * 8] = (bf16)acc[mt][nt][r];
      }
    }
  }
}

// ---------------- flash attention: lockstep waves + dbuf DMA; packed-A output ----------------
__global__ __launch_bounds__(256, 2) void flash_k(const bf16* __restrict__ Q,
                                                  const bf16* __restrict__ Kp,
                                                  const bf16* __restrict__ Vp,
                                                  const float* __restrict__ amask,
                                                  bf16* __restrict__ Ap2) {
  __shared__ __align__(16) bf16 stage[2][16384];
  __shared__ __align__(16) bf16 pbuf[4][16 * 72];
  int blk = blockIdx.x;
  int bh = blk & 31;
  int ab = blk >> 5;
  int b = bh >> 4, h = bh & 15;
  int t = threadIdx.x;
  int w = t >> 6, l = t & 63;
  int quad = l >> 4, ln = l & 15;

  const bf16* Kpb = Kp + (size_t)bh * (S_ * D_);
  const bf16* Vpb = Vp + (size_t)bh * (S_ * D_);
  const float* mbase = amask + (size_t)b * S_;
  bf16* pw = pbuf[w];

#pragma unroll
  for (int j = 0; j < 8; j++) {
    int gi = w * 8 + j;
    const bf16* src = (gi < 16 ? Kpb + gi * 512 : Vpb + (gi - 16) * 512) + l * 8;
    gload_lds16(src, stage[0] + gi * 512);
  }

  int it = 0;
#pragma unroll 1
  for (int phase = 0; phase < 2; phase++) {
    int a = phase ? (31 - ab) : ab;
    int strip = a * 4 + w;
    int qs = strip * 16;
    int T = a + 1;

    const bf16* Qp = Q + (size_t)(bh * S_ + qs + ln) * D_;
    bf16x8 qf[4];
#pragma unroll
    for (int ks = 0; ks < 4; ks++)
      qf[ks] = *(const bf16x8*)(Qp + ks * 32 + quad * 8);

    floatx4 oacc[8] = {};
    float m_i = -1e30f, l_i = 0.f;

#pragma unroll 1
    for (int kt = 0; kt < T; kt++, it++) {
      __syncthreads();
      const bf16* cur = stage[it & 1];
      if (it != 32) {
        int nkv = (kt + 1 < T) ? (kt + 1) : 0;
        bf16* nb = stage[(it + 1) & 1];
#pragma unroll
        for (int j = 0; j < 8; j++) {
          int gi = w * 8 + j;
          const bf16* src = (gi < 16 ? Kpb + (size_t)nkv * 8192 + gi * 512
                                     : Vpb + (size_t)nkv * 8192 + (gi - 16) * 512) + l * 8;
          gload_lds16(src, nb + gi * 512);
        }
      }
      int kv0 = kt * 64;

      floatx4 acc[4] = {};
#pragma unroll
      for (int ks = 0; ks < 4; ks++)
#pragma unroll
        for (int mt = 0; mt < 4; mt++) {
          bf16x8 kf = *(const bf16x8*)(cur + (mt * 4 + ks) * 512 + l * 8);
          acc[mt] = MFMA16(kf, qf[ks], acc[mt]);
        }

      floatx4 am4[4];
#pragma unroll
      for (int mt = 0; mt < 4; mt++)
        am4[mt] = *(const floatx4*)(mbase + kv0 + mt * 16 + quad * 4);

      bool diag = (kt == T - 1);
      int q = qs + ln;
      float v[4][4];
      float mx = -3.0e38f;
#pragma unroll
      for (int mt = 0; mt < 4; mt++)
#pragma unroll
        for (int r = 0; r < 4; r++) {
          float x = acc[mt][r] + am4[mt][r] * LOG2E;
          if (diag && (kv0 + mt * 16 + quad * 4 + r > q)) x = -3.0e38f;
          v[mt][r] = x;
          mx = fmaxf(mx, x);
        }
      mx = fmaxf(mx, __shfl_xor(mx, 16, 64));
      mx = fmaxf(mx, __shfl_xor(mx, 32, 64));
      // T13 defer-max: only rescale when some row's max grew by > 8 (log2).
      if (__any(mx > m_i + 8.0f)) {
        float mnew = fmaxf(m_i, mx);
        float alpha = exp2f(m_i - mnew);
        l_i *= alpha;
#pragma unroll
        for (int dt = 0; dt < 8; dt++) oacc[dt] *= alpha;
        m_i = mnew;
      }
      float sum = 0.f;
      bf16x4 pk[4];
#pragma unroll
      for (int mt = 0; mt < 4; mt++)
#pragma unroll
        for (int r = 0; r < 4; r++) {
          float p = exp2f(v[mt][r] - m_i);
          sum += p;
          pk[mt][r] = (bf16)p;
        }
      sum += __shfl_xor(sum, 16, 64);
      sum += __shfl_xor(sum, 32, 64);
      l_i += sum;

#pragma unroll
      for (int mt = 0; mt < 4; mt++)
        *(bf16x4*)(pw + ln * 72 + mt * 16 + quad * 4) = pk[mt];

      const bf16* vcur = cur + 8192;
#pragma unroll
      for (int ks = 0; ks < 2; ks++) {
        bf16x8 pf = *(const bf16x8*)(pw + ln * 72 + ks * 32 + quad * 8);
#pragma unroll
        for (int dt = 0; dt < 8; dt++) {
          bf16x8 vf = *(const bf16x8*)(vcur + (dt * 2 + ks) * 512 + l * 8);
          oacc[dt] = MFMA16(vf, pf, oacc[dt]);
        }
      }
    }

    // epilogue: normalize + store directly in gemm2's packed-A layout
    float inv_l = 1.0f / l_i;
    int mrow = b * S_ + qs;  // multiple of 16
    int mb2 = mrow >> 7;
    int cc = (mrow >> 4) & 7;
    bf16* abase = Ap2 + ((size_t)mb2 * 64 * 8 + cc) * 512;
#pragma unroll
    for (int dt = 0; dt < 8; dt++) {
      bf16x4 ov;
#pragma unroll
      for (int r = 0; r < 4; r++) ov[r] = (bf16)(oacc[dt][r] * inv_l);
      int kb2 = h * 4 + (dt >> 1);
      int lp = ((dt & 1) * 2 + (quad >> 1)) * 16 + ln;
      *(bf16x4*)(abase + (size_t)kb2 * 4096 + lp * 8 + (quad & 1) * 4) = ov;
    }
  }
}

// ---------------- launch ----------------
extern "C" void kernel_launch(void* const* d_in, const int* in_sizes, int n_in,
                              void* d_out, int out_size, void* d_ws, size_t ws_size,
                              hipStream_t stream) {
  const float* hidden = (const float*)d_in[0];
  const float* amask = (const float*)d_in[1];
  const float* Wqkv = (const float*)d_in[2];
  const float* Wdense = (const float*)d_in[3];
  const int* posids = (const int*)d_in[4];
  float* out = (float*)d_out;
  char* ws = (char*)d_ws;

  // workspace layout (101.7 MB of the 125.8 MB used; all live ranges disjoint):
  //  [0,        8.39M)  Bp2 (Wdense packed)       — lives until gemm2
  //  [8.39M,  25.17M)  Ap1 (hidden packed) -> Ap2 (attn packed, written by flash)
  //  [25.17M, 50.33M)  Bp1 (Wqkv packed)          — read by gemm_qkv
  //  [50.33M, 67.11M)  Q   (written by gemm_qkv epilogue)
  //  [67.11M, 83.89M)  Kp
  //  [83.89M,100.66M)  Vp
  //  [100.66M,101.71M) rotary LUT (float4 x 4096 x 16)
  bf16* Bp2 = (bf16*)(ws + 0);
  bf16* Ap1 = (bf16*)(ws + 8388608ull);
  bf16* Ap2 = (bf16*)(ws + 8388608ull);
  bf16* Bp1 = (bf16*)(ws + 25165824ull);
  bf16* Qb = (bf16*)(ws + 50331648ull);
  bf16* Kpb = (bf16*)(ws + 67108864ull);
  bf16* Vpb = (bf16*)(ws + 83886080ull);
  float4* lut = (float4*)(ws + 100663296ull);

  rotlut_k<<<256, 256, 0, stream>>>(posids, lut);
  pack_a_k<<<dim3(32, 64), 256, 0, stream>>>(hidden, Ap1, 2048, 64);
  pack_b_k<<<dim3(48, 64), 256, 0, stream>>>(Wqkv, Bp1, 6144, 64);
  pack_b_k<<<dim3(16, 64), 256, 0, stream>>>(Wdense, Bp2, 2048, 64);
  gemm_qkv_k<<<dim3(32, 48), 256, 0, stream>>>(Ap1, Bp1, lut, Qb, Kpb, Vpb, 64);
  flash_k<<<512, 256, 0, stream>>>(Qb, Kpb, Vpb, amask, Ap2);
  gemm_p_k<float><<<dim3(32, 16), 256, 0, stream>>>(Ap2, Bp2, out, 2048, 64);
}

// Round 5
// 334.329 us; speedup vs baseline: 1.2455x; 1.0802x over previous
//
#include <hip/hip_runtime.h>
#include <stdint.h>

#define B_ 2
#define S_ 2048
#define HID_ 2048
#define H_ 16
#define D_ 128
#define LOG2E 1.44269504088896f

typedef __bf16 bf16;
typedef __bf16 bf16x8 __attribute__((ext_vector_type(8)));
typedef __bf16 bf16x4 __attribute__((ext_vector_type(4)));
typedef float floatx4 __attribute__((ext_vector_type(4)));

#define MFMA16(a, b, c) __builtin_amdgcn_mfma_f32_16x16x32_bf16(a, b, c, 0, 0, 0)

__device__ __forceinline__ void gload_lds16(const bf16* g, bf16* l) {
  __builtin_amdgcn_global_load_lds(
      (const __attribute__((address_space(1))) uint32_t*)g,
      (__attribute__((address_space(3))) uint32_t*)l, 16, 0, 0);
}

// ---------------- unified prep kernel ----------------
// Round-5: rotlut + pack_a + pack_b(Wqkv) + pack_b(Wdense) merged into ONE
// dispatch (7 -> 4 total). Budget audit says inter-dispatch gaps ~10 us each
// are a top-3 cost; this removes 3 of them and lets the 4 independent jobs
// co-schedule across CUs.
//   blocks [0,256):        rotlut  (4096*16 entries)
//   blocks [256,2304):     pack_a  hidden (32 x 64 tile grid)
//   blocks [2304,5376):    pack_b  Wqkv   (48 x 64)
//   blocks [5376,6400):    pack_b  Wdense (16 x 64)
__device__ __forceinline__ void pack_a_body(const float* __restrict__ in,
                                            bf16* __restrict__ out,
                                            int K, int nk, int mb, int kb) {
  int t = threadIdx.x;
  int c = t >> 5, sub = t & 31;
  bf16* obase = out + (((size_t)mb * nk + kb) * 8 + c) * 512;
#pragma unroll
  for (int i = 0; i < 2; i++) {
    int l = sub * 2 + i;
    int row = mb * 128 + c * 16 + (l & 15);
    int col = kb * 32 + (l >> 4) * 8;
    const float* ip = in + (size_t)row * K + col;
    float4 a = *(const float4*)ip;
    float4 b2 = *(const float4*)(ip + 4);
    bf16x8 o;
    o[0] = (bf16)a.x; o[1] = (bf16)a.y; o[2] = (bf16)a.z; o[3] = (bf16)a.w;
    o[4] = (bf16)b2.x; o[5] = (bf16)b2.y; o[6] = (bf16)b2.z; o[7] = (bf16)b2.w;
    *(bf16x8*)(obase + l * 8) = o;
  }
}

__device__ __forceinline__ void pack_b_body(const float* __restrict__ W,
                                            bf16* __restrict__ out,
                                            int N, int nk, int nb, int kb,
                                            float (*ftile)[132]) {
  int t = threadIdx.x;
#pragma unroll
  for (int p = 0; p < 4; p++) {
    int row = p * 8 + (t >> 5);
    int col = (t & 31) * 4;
    float4 v = *(const float4*)(W + (size_t)(kb * 32 + row) * N + nb * 128 + col);
    *(float4*)&ftile[row][col] = v;
  }
  __syncthreads();
  int c = t >> 5, sub = t & 31;
  bf16* obase = out + (((size_t)nb * nk + kb) * 8 + c) * 512;
#pragma unroll
  for (int i = 0; i < 2; i++) {
    int l = sub * 2 + i;
    int rbase = (l >> 4) * 8;
    int coln = c * 16 + (l & 15);
    bf16x8 o;
#pragma unroll
    for (int j = 0; j < 8; j++) o[j] = (bf16)ftile[rbase + j][coln];
    *(bf16x8*)(obase + l * 8) = o;
  }
}

__global__ __launch_bounds__(256) void prep_k(const float* __restrict__ hidden,
                                              const float* __restrict__ Wqkv,
                                              const float* __restrict__ Wdense,
                                              const int* __restrict__ pos_ids,
                                              bf16* __restrict__ Ap1,
                                              bf16* __restrict__ Bp1,
                                              bf16* __restrict__ Bp2,
                                              float4* __restrict__ lut) {
  __shared__ float ftile[32][132];
  int bid = blockIdx.x;
  if (bid < 256) {
    int idx = bid * 256 + threadIdx.x;  // idx = row*16 + i
    int row = idx >> 4, i = idx & 15;
    float tp = (float)pos_ids[row];
    float invf = powf(10000.f, -(float)i * (1.f / 16.f));
    float fr = tp * invf;
    float cs = cosf(fr), sn = sinf(fr);
    float scl = ((float)(2 * i) + 12.8f) * (1.f / 44.8f);
    float sc = powf(scl, (tp - 1024.f) * (1.f / 512.f));
    float4 o;
    o.x = cs * sc;
    o.y = sn * sc;
    o.z = cs / sc;
    o.w = sn / sc;
    lut[idx] = o;
  } else if (bid < 2304) {
    int v = bid - 256;
    pack_a_body(hidden, Ap1, 2048, 64, v & 31, v >> 5);
  } else if (bid < 5376) {
    int v = bid - 2304;
    pack_b_body(Wqkv, Bp1, 6144, 64, v % 48, v / 48, ftile);
  } else {
    int v = bid - 5376;
    pack_b_body(Wdense, Bp2, 2048, 64, v & 15, v >> 4, ftile);
  }
}

// ---------------- GEMM on packed operands: dbuf LDS, 1 barrier/iter ----------------
template <typename OutT>
__global__ __launch_bounds__(256, 2) void gemm_p_k(const bf16* __restrict__ Ap,
                                                   const bf16* __restrict__ Bp,
                                                   OutT* __restrict__ C,
                                                   int N, int nk) {
  __shared__ __align__(16) bf16 stage[2][8192];
  const int t = threadIdx.x;
  const int w = t >> 6, l = t & 63;
  const int quad = l >> 4, ln = l & 15;
  const int wm = w >> 1, wn = w & 1;
  const int mb = blockIdx.x, nb = blockIdx.y;

  const bf16* sbase = (w < 2 ? Ap + ((size_t)mb * nk * 8 + w * 4) * 512
                             : Bp + ((size_t)nb * nk * 8 + (w - 2) * 4) * 512) + l * 8;
  bf16* dbase0 = stage[0] + w * 2048;
  bf16* dbase1 = stage[1] + w * 2048;

  floatx4 acc[4][4] = {};

#pragma unroll
  for (int i = 0; i < 4; i++) gload_lds16(sbase + i * 512, dbase0 + i * 512);

  for (int kb = 0; kb < nk; kb++) {
    __syncthreads();
    if (kb + 1 < nk) {
      const bf16* s = sbase + (size_t)(kb + 1) * 4096;
      bf16* d = ((kb + 1) & 1) ? dbase1 : dbase0;
#pragma unroll
      for (int i = 0; i < 4; i++) gload_lds16(s + i * 512, d + i * 512);
    }
    const bf16* cur = stage[kb & 1];
    bf16x8 af[4], bfr[4];
#pragma unroll
    for (int mt = 0; mt < 4; mt++)
      af[mt] = *(const bf16x8*)(cur + (wm * 4 + mt) * 512 + l * 8);
#pragma unroll
    for (int nt = 0; nt < 4; nt++)
      bfr[nt] = *(const bf16x8*)(cur + 4096 + (wn * 4 + nt) * 512 + l * 8);
#pragma unroll
    for (int mt = 0; mt < 4; mt++)
#pragma unroll
      for (int nt = 0; nt < 4; nt++)
        acc[mt][nt] = MFMA16(af[mt], bfr[nt], acc[mt][nt]);
  }

  const int m0 = mb * 128, n0 = nb * 128;
#pragma unroll
  for (int mt = 0; mt < 4; mt++)
#pragma unroll
    for (int nt = 0; nt < 4; nt++) {
      int row = m0 + wm * 64 + mt * 16 + quad * 4;
      int col = n0 + wn * 64 + nt * 16 + ln;
      OutT* cp = C + (size_t)row * N + col;
#pragma unroll
      for (int r = 0; r < 4; r++)
        cp[(size_t)r * N] = (OutT)acc[mt][nt][r];
    }
}

// ---------------- fused QKV GEMM: rotary (via LUT) + scale + Q/Kp/Vp scatter ----------
__global__ __launch_bounds__(256, 2) void gemm_qkv_k(const bf16* __restrict__ Ap,
                                                     const bf16* __restrict__ Bp,
                                                     const float4* __restrict__ lut,
                                                     bf16* __restrict__ Q,
                                                     bf16* __restrict__ Kp,
                                                     bf16* __restrict__ Vp,
                                                     int nk) {
  __shared__ __align__(16) bf16 stage[2][8192];
  const int t = threadIdx.x;
  const int w = t >> 6, l = t & 63;
  const int quad = l >> 4, ln = l & 15;
  const int wm = w >> 1, wn = w & 1;
  const int mb = blockIdx.x, nb = blockIdx.y;

  const bf16* sbase = (w < 2 ? Ap + ((size_t)mb * nk * 8 + w * 4) * 512
                             : Bp + ((size_t)nb * nk * 8 + (w - 2) * 4) * 512) + l * 8;
  bf16* dbase0 = stage[0] + w * 2048;
  bf16* dbase1 = stage[1] + w * 2048;

  floatx4 acc[4][4] = {};

#pragma unroll
  for (int i = 0; i < 4; i++) gload_lds16(sbase + i * 512, dbase0 + i * 512);

  for (int kb = 0; kb < nk; kb++) {
    __syncthreads();
    if (kb + 1 < nk) {
      const bf16* s = sbase + (size_t)(kb + 1) * 4096;
      bf16* d = ((kb + 1) & 1) ? dbase1 : dbase0;
#pragma unroll
      for (int i = 0; i < 4; i++) gload_lds16(s + i * 512, d + i * 512);
    }
    const bf16* cur = stage[kb & 1];
    bf16x8 af[4], bfr[4];
#pragma unroll
    for (int mt = 0; mt < 4; mt++)
      af[mt] = *(const bf16x8*)(cur + (wm * 4 + mt) * 512 + l * 8);
#pragma unroll
    for (int nt = 0; nt < 4; nt++)
      bfr[nt] = *(const bf16x8*)(cur + 4096 + (wn * 4 + nt) * 512 + l * 8);
#pragma unroll
    for (int mt = 0; mt < 4; mt++)
#pragma unroll
      for (int nt = 0; nt < 4; nt++)
        acc[mt][nt] = MFMA16(af[mt], bfr[nt], acc[mt][nt]);
  }

  // ---- epilogue: acc[mt][nt][r] at row = mb*128+wm*64+mt*16+quad*4+r,
  //      d = wn*64 + nt*16 + ln
  const int h = nb / 3;
  const int type = nb - h * 3;
  const int m0 = mb * 128;

  if (type == 2) {
#pragma unroll
    for (int mt = 0; mt < 4; mt++) {
      int row0 = m0 + wm * 64 + mt * 16 + quad * 4;
      int b = row0 >> 11, s0 = row0 & 2047;
      size_t vb = (size_t)(b * 16 + h) * (S_ * D_) + (size_t)(s0 >> 6) * 8192;
      int lf = ((mt & 1) * 2 + (quad >> 1)) * 16 + ln;
      int j0 = (quad & 1) * 4;
#pragma unroll
      for (int nt = 0; nt < 4; nt++) {
        int cv = (wn * 4 + nt) * 2 + (mt >> 1);
        bf16x4 ov;
#pragma unroll
        for (int r = 0; r < 4; r++) ov[r] = (bf16)acc[mt][nt][r];
        *(bf16x4*)(Vp + vb + cv * 512 + lf * 8 + j0) = ov;
      }
    }
    return;
  }

  if (wn == 0) {  // rotary covers dims 0..31 = (nt=0, nt=1) pairs; wave-uniform
#pragma unroll
    for (int mt = 0; mt < 4; mt++)
#pragma unroll
      for (int r = 0; r < 4; r++) {
        int row = m0 + wm * 64 + mt * 16 + quad * 4 + r;
        float4 cf = lut[row * 16 + ln];
        float c_ = (type == 0) ? cf.x : cf.z;
        float s_ = (type == 0) ? cf.y : cf.w;
        float x1 = acc[mt][0][r], x2 = acc[mt][1][r];
        acc[mt][0][r] = x1 * c_ - x2 * s_;
        acc[mt][1][r] = x2 * c_ + x1 * s_;
      }
  }

  if (type == 0) {
    const float QS = 0.08838834764831845f * LOG2E;
#pragma unroll
    for (int mt = 0; mt < 4; mt++) {
      int row0 = m0 + wm * 64 + mt * 16 + quad * 4;
      int b = row0 >> 11, s0 = row0 & 2047;
      bf16* qb = Q + ((size_t)(b * 16 + h) * S_ + s0) * D_ + wn * 64 + ln;
#pragma unroll
      for (int nt = 0; nt < 4; nt++)
#pragma unroll
        for (int r = 0; r < 4; r++)
          qb[(size_t)r * D_ + nt * 16] = (bf16)(acc[mt][nt][r] * QS);
    }
  } else {
#pragma unroll
    for (int mt = 0; mt < 4; mt++) {
      int row0 = m0 + wm * 64 + mt * 16 + quad * 4;
      int b = row0 >> 11, s0 = row0 & 2047;
      bf16* kb_ = Kp + (size_t)(b * 16 + h) * (S_ * D_) + (size_t)(s0 >> 6) * 8192 + (ln & 7);
#pragma unroll
      for (int nt = 0; nt < 4; nt++) {
        int ck = mt * 4 + wn * 2 + (nt >> 1);
        int lp = ((nt & 1) * 2 + (ln >> 3)) * 16 + quad * 4;
#pragma unroll
        for (int r = 0; r < 4; r++)
          kb_[ck * 512 + (lp + r) * 8] = (bf16)acc[mt][nt][r];
      }
    }
  }
}

// ---------------- flash attention: lockstep waves + dbuf DMA; packed-A output ----------------
// Round-5: diag-mask branch hoisted out of the element loop (block-uniform),
// amask loads issued before the QK MFMA cluster so latency hides under MFMA.
__global__ __launch_bounds__(256, 2) void flash_k(const bf16* __restrict__ Q,
                                                  const bf16* __restrict__ Kp,
                                                  const bf16* __restrict__ Vp,
                                                  const float* __restrict__ amask,
                                                  bf16* __restrict__ Ap2) {
  __shared__ __align__(16) bf16 stage[2][16384];
  __shared__ __align__(16) bf16 pbuf[4][16 * 72];
  int blk = blockIdx.x;
  int bh = blk & 31;
  int ab = blk >> 5;
  int b = bh >> 4, h = bh & 15;
  int t = threadIdx.x;
  int w = t >> 6, l = t & 63;
  int quad = l >> 4, ln = l & 15;

  const bf16* Kpb = Kp + (size_t)bh * (S_ * D_);
  const bf16* Vpb = Vp + (size_t)bh * (S_ * D_);
  const float* mbase = amask + (size_t)b * S_;
  bf16* pw = pbuf[w];

#pragma unroll
  for (int j = 0; j < 8; j++) {
    int gi = w * 8 + j;
    const bf16* src = (gi < 16 ? Kpb + gi * 512 : Vpb + (gi - 16) * 512) + l * 8;
    gload_lds16(src, stage[0] + gi * 512);
  }

  int it = 0;
#pragma unroll 1
  for (int phase = 0; phase < 2; phase++) {
    int a = phase ? (31 - ab) : ab;
    int strip = a * 4 + w;
    int qs = strip * 16;
    int T = a + 1;

    const bf16* Qp = Q + (size_t)(bh * S_ + qs + ln) * D_;
    bf16x8 qf[4];
#pragma unroll
    for (int ks = 0; ks < 4; ks++)
      qf[ks] = *(const bf16x8*)(Qp + ks * 32 + quad * 8);

    floatx4 oacc[8] = {};
    float m_i = -1e30f, l_i = 0.f;

#pragma unroll 1
    for (int kt = 0; kt < T; kt++, it++) {
      __syncthreads();
      const bf16* cur = stage[it & 1];
      if (it != 32) {
        int nkv = (kt + 1 < T) ? (kt + 1) : 0;
        bf16* nb = stage[(it + 1) & 1];
#pragma unroll
        for (int j = 0; j < 8; j++) {
          int gi = w * 8 + j;
          const bf16* src = (gi < 16 ? Kpb + (size_t)nkv * 8192 + gi * 512
                                     : Vpb + (size_t)nkv * 8192 + (gi - 16) * 512) + l * 8;
          gload_lds16(src, nb + gi * 512);
        }
      }
      int kv0 = kt * 64;

      // issue mask loads first: latency hides under the QK MFMA cluster
      floatx4 am4[4];
#pragma unroll
      for (int mt = 0; mt < 4; mt++)
        am4[mt] = *(const floatx4*)(mbase + kv0 + mt * 16 + quad * 4);

      floatx4 acc[4] = {};
#pragma unroll
      for (int ks = 0; ks < 4; ks++)
#pragma unroll
        for (int mt = 0; mt < 4; mt++) {
          bf16x8 kf = *(const bf16x8*)(cur + (mt * 4 + ks) * 512 + l * 8);
          acc[mt] = MFMA16(kf, qf[ks], acc[mt]);
        }

      float v[4][4];
      float mx = -3.0e38f;
      if (kt == T - 1) {  // diag tile: apply causal mask (block-uniform branch)
        int q = qs + ln;
#pragma unroll
        for (int mt = 0; mt < 4; mt++)
#pragma unroll
          for (int r = 0; r < 4; r++) {
            float x = acc[mt][r] + am4[mt][r] * LOG2E;
            if (kv0 + mt * 16 + quad * 4 + r > q) x = -3.0e38f;
            v[mt][r] = x;
            mx = fmaxf(mx, x);
          }
      } else {
#pragma unroll
        for (int mt = 0; mt < 4; mt++)
#pragma unroll
          for (int r = 0; r < 4; r++) {
            float x = acc[mt][r] + am4[mt][r] * LOG2E;
            v[mt][r] = x;
            mx = fmaxf(mx, x);
          }
      }
      mx = fmaxf(mx, __shfl_xor(mx, 16, 64));
      mx = fmaxf(mx, __shfl_xor(mx, 32, 64));
      // T13 defer-max: only rescale when some row's max grew by > 8 (log2).
      if (__any(mx > m_i + 8.0f)) {
        float mnew = fmaxf(m_i, mx);
        float alpha = exp2f(m_i - mnew);
        l_i *= alpha;
#pragma unroll
        for (int dt = 0; dt < 8; dt++) oacc[dt] *= alpha;
        m_i = mnew;
      }
      float sum = 0.f;
      bf16x4 pk[4];
#pragma unroll
      for (int mt = 0; mt < 4; mt++)
#pragma unroll
        for (int r = 0; r < 4; r++) {
          float p = exp2f(v[mt][r] - m_i);
          sum += p;
          pk[mt][r] = (bf16)p;
        }
      sum += __shfl_xor(sum, 16, 64);
      sum += __shfl_xor(sum, 32, 64);
      l_i += sum;

#pragma unroll
      for (int mt = 0; mt < 4; mt++)
        *(bf16x4*)(pw + ln * 72 + mt * 16 + quad * 4) = pk[mt];

      const bf16* vcur = cur + 8192;
#pragma unroll
      for (int ks = 0; ks < 2; ks++) {
        bf16x8 pf = *(const bf16x8*)(pw + ln * 72 + ks * 32 + quad * 8);
#pragma unroll
        for (int dt = 0; dt < 8; dt++) {
          bf16x8 vf = *(const bf16x8*)(vcur + (dt * 2 + ks) * 512 + l * 8);
          oacc[dt] = MFMA16(vf, pf, oacc[dt]);
        }
      }
    }

    // epilogue: normalize + store directly in gemm2's packed-A layout
    float inv_l = 1.0f / l_i;
    int mrow = b * S_ + qs;  // multiple of 16
    int mb2 = mrow >> 7;
    int cc = (mrow >> 4) & 7;
    bf16* abase = Ap2 + ((size_t)mb2 * 64 * 8 + cc) * 512;
#pragma unroll
    for (int dt = 0; dt < 8; dt++) {
      bf16x4 ov;
#pragma unroll
      for (int r = 0; r < 4; r++) ov[r] = (bf16)(oacc[dt][r] * inv_l);
      int kb2 = h * 4 + (dt >> 1);
      int lp = ((dt & 1) * 2 + (quad >> 1)) * 16 + ln;
      *(bf16x4*)(abase + (size_t)kb2 * 4096 + lp * 8 + (quad & 1) * 4) = ov;
    }
  }
}

// ---------------- launch ----------------
extern "C" void kernel_launch(void* const* d_in, const int* in_sizes, int n_in,
                              void* d_out, int out_size, void* d_ws, size_t ws_size,
                              hipStream_t stream) {
  const float* hidden = (const float*)d_in[0];
  const float* amask = (const float*)d_in[1];
  const float* Wqkv = (const float*)d_in[2];
  const float* Wdense = (const float*)d_in[3];
  const int* posids = (const int*)d_in[4];
  float* out = (float*)d_out;
  char* ws = (char*)d_ws;

  // workspace layout (101.7 MB used; all live ranges disjoint):
  //  [0,        8.39M)  Bp2 (Wdense packed)       — lives until gemm2
  //  [8.39M,  25.17M)  Ap1 (hidden packed) -> Ap2 (attn packed, written by flash)
  //  [25.17M, 50.33M)  Bp1 (Wqkv packed)          — read by gemm_qkv
  //  [50.33M, 67.11M)  Q
  //  [67.11M, 83.89M)  Kp
  //  [83.89M,100.66M)  Vp
  //  [100.66M,101.71M) rotary LUT (float4 x 4096 x 16)
  bf16* Bp2 = (bf16*)(ws + 0);
  bf16* Ap1 = (bf16*)(ws + 8388608ull);
  bf16* Ap2 = (bf16*)(ws + 8388608ull);
  bf16* Bp1 = (bf16*)(ws + 25165824ull);
  bf16* Qb = (bf16*)(ws + 50331648ull);
  bf16* Kpb = (bf16*)(ws + 67108864ull);
  bf16* Vpb = (bf16*)(ws + 83886080ull);
  float4* lut = (float4*)(ws + 100663296ull);

  prep_k<<<6400, 256, 0, stream>>>(hidden, Wqkv, Wdense, posids, Ap1, Bp1, Bp2, lut);
  gemm_qkv_k<<<dim3(32, 48), 256, 0, stream>>>(Ap1, Bp1, lut, Qb, Kpb, Vpb, 64);
  flash_k<<<512, 256, 0, stream>>>(Qb, Kpb, Vpb, amask, Ap2);
  gemm_p_k<float><<<dim3(32, 16), 256, 0, stream>>>(Ap2, Bp2, out, 2048, 64);
}